// Round 1
// baseline (1114.179 us; speedup 1.0000x reference)
//
#include <hip/hip_runtime.h>
#include <math.h>

#define N_NODES 30000
#define N_EDGES 480000
#define HDIM 128
#define EPB 64        // edges (or nodes) per MFMA block; max node degree (~40)
                      // must be < EPB so a node's CSR range spans <=2 blocks.
#define AS 296        // edge A-tile row stride (ushort) = 592 B = 148 f32
#define NAS 264       // node A-tile row stride (ushort)

typedef __attribute__((ext_vector_type(8))) short short8b;
typedef __attribute__((ext_vector_type(4))) float f32x4;

__device__ __forceinline__ float silu_f(float v) {
  return v / (1.0f + __expf(-v));
}

__device__ __forceinline__ unsigned short f2bf(float f) {
  unsigned int u = __float_as_uint(f);
  unsigned int r = u + 0x7fffu + ((u >> 16) & 1u);
  return (unsigned short)(r >> 16);
}

// ---------------- output init: out = [h | x] ----------------
__global__ void init_out_kernel(const float* __restrict__ h,
                                const float* __restrict__ x,
                                float* __restrict__ out) {
  int idx = blockIdx.x * 256 + threadIdx.x;
  out[idx] = h[idx];
  if (idx < N_NODES * 3) out[N_NODES * HDIM + idx] = x[idx];
}

// ---------------- h (fp32) -> hbf (bf16) ----------------
__global__ void h_to_bf_kernel(const float* __restrict__ h,
                               ushort* __restrict__ hbf) {
  int idx = blockIdx.x * 256 + threadIdx.x;
  float4 v = ((const float4*)h)[idx];
  ushort4 o;
  o.x = f2bf(v.x); o.y = f2bf(v.y); o.z = f2bf(v.z); o.w = f2bf(v.w);
  ((ushort4*)hbf)[idx] = o;
}

// ---------------- weight convert: W[K][128] fp32 -> [KT][128][32] bf16 ----
// Column order is PERMUTED so that the MFMA C-layout of output tiles 2c,2c+1
// directly forms the B-fragment (8 consecutive k at lq*8) of the next GEMM:
//   tile row p (0..127) holds true column
//   n = (p>>5)*32 + ((p>>2)&3)*8 + ((p>>4)&1)*4 + (p&3)     (bijective)
// All weight matrices (w1,w2,enc,wqd,cw1,cw2) use this layout; biases and
// output writes use the matching 4-consecutive base nb(t) = (t>>1)*32+lq*8+(t&1)*4.
__global__ void convert_w_kernel(const float* __restrict__ W,
                                 ushort* __restrict__ dst, int Kreal, int KT) {
  int idx = blockIdx.x * 256 + threadIdx.x;
  if (idx >= KT * 4096) return;
  int kt = idx >> 12, rem = idx & 4095, p = rem >> 5, kk = rem & 31;
  int n = ((p >> 5) << 5) | (((p >> 2) & 3) << 3) | (((p >> 4) & 1) << 2) | (p & 3);
  int k = kt * 32 + kk;
  float v = (k < Kreal) ? W[(size_t)k * HDIM + n] : 0.0f;
  dst[idx] = f2bf(v);
}

// ---------------- counting sort of edges by destination row ----------------
__global__ void count_kernel(const int* __restrict__ ei, int* __restrict__ cursor) {
  int e = blockIdx.x * 256 + threadIdx.x;
  atomicAdd(&cursor[ei[e]], 1);
}

__global__ __launch_bounds__(1024) void scan_kernel(int* __restrict__ cursor,
                                                    int* __restrict__ cstart) {
  __shared__ int sums[1024];
  const int tid = threadIdx.x;
  const int base = tid * 30;
  int local[30];
  int s = 0;
#pragma unroll
  for (int j = 0; j < 30; ++j) {
    int idx = base + j;
    int d = (idx < N_NODES) ? cursor[idx] : 0;
    local[j] = s;
    s += d;
  }
  sums[tid] = s;
  __syncthreads();
  for (int off = 1; off < 1024; off <<= 1) {
    int add = (tid >= off) ? sums[tid - off] : 0;
    __syncthreads();
    sums[tid] += add;
    __syncthreads();
  }
  int excl = (tid == 0) ? 0 : sums[tid - 1];
#pragma unroll
  for (int j = 0; j < 30; ++j) {
    int idx = base + j;
    if (idx < N_NODES) {
      int v = excl + local[j];
      cursor[idx] = v;
      cstart[idx] = v;   // immutable CSR starts (cursor mutates in fill)
    }
  }
}

__global__ void fill_kernel(const int* __restrict__ ei, int* __restrict__ cursor,
                            int* __restrict__ elist) {
  int e = blockIdx.x * 256 + threadIdx.x;
  int r = ei[e];
  int pos = atomicAdd(&cursor[r], 1);   // after this kernel cursor[n] = CSR end
  elist[pos] = e;
}

// ---------------- CNOT ring permutation ----------------
__global__ void perm_kernel(int* __restrict__ g) {
  int i = threadIdx.x;
  int v = i;
  const int cs[7] = {6, 5, 4, 3, 2, 1, 0};
  const int ts[7] = {0, 6, 5, 4, 3, 2, 1};
#pragma unroll
  for (int p = 0; p < 7; ++p) {
    int cb = (v >> (6 - cs[p])) & 1;
    v = v ^ (cb << (6 - ts[p]));
  }
  g[i] = v;
}

// ============ Newton-Schulz inverse of B = A_h + iI ============
__global__ void ns_init_kernel(const float* __restrict__ Are,
                               const float* __restrict__ Aim,
                               float2* __restrict__ X) {
  int lj = blockIdx.y;
  int idx = blockIdx.x * 256 + threadIdx.x;
  int r = idx >> 7, c = idx & 127;
  const float* are = Are + (size_t)lj * 16384;
  const float* aim = Aim + (size_t)lj * 16384;
  float re = are[r * 128 + c] + are[c * 128 + r];
  float im = aim[r * 128 + c] - aim[c * 128 + r];
  if (r == c) im -= 1.0f;
  X[(size_t)lj * 16384 + idx] = make_float2(re, im);
}

__global__ void ns_bx_kernel(const float* __restrict__ Are,
                             const float* __restrict__ Aim,
                             const float2* __restrict__ X,
                             float2* __restrict__ T) {
  int lj = blockIdx.y;
  int idx = blockIdx.x * 256 + threadIdx.x;
  int r = idx >> 7, c = idx & 127;
  const float* are = Are + (size_t)lj * 16384;
  const float* aim = Aim + (size_t)lj * 16384;
  const float2* x = X + (size_t)lj * 16384;
  float2 acc = make_float2(0.f, 0.f);
  for (int k = 0; k < 128; ++k) {
    float re = are[r * 128 + k] + are[k * 128 + r];
    float im = aim[r * 128 + k] - aim[k * 128 + r];
    if (k == r) im += 1.0f;
    float2 b = x[k * 128 + c];
    acc.x += re * b.x - im * b.y;
    acc.y += re * b.y + im * b.x;
  }
  T[(size_t)lj * 16384 + idx] = acc;
}

__global__ void ns_upd_kernel(const float2* __restrict__ X,
                              const float2* __restrict__ T,
                              float2* __restrict__ Xn) {
  int lj = blockIdx.y;
  int idx = blockIdx.x * 256 + threadIdx.x;
  int r = idx >> 7, c = idx & 127;
  const float2* x = X + (size_t)lj * 16384;
  const float2* t = T + (size_t)lj * 16384;
  float2 acc = make_float2(0.f, 0.f);
  for (int k = 0; k < 128; ++k) {
    float2 a = x[r * 128 + k];
    float2 b = t[k * 128 + c];
    acc.x += a.x * b.x - a.y * b.y;
    acc.y += a.x * b.y + a.y * b.x;
  }
  float2 xc = x[r * 128 + c];
  Xn[(size_t)lj * 16384 + idx] = make_float2(2.f * xc.x - acc.x, 2.f * xc.y - acc.y);
}

// ---------------- q = (A_h - iI) * Binv ----------------
__global__ void qmat_kernel(const float* __restrict__ Are,
                            const float* __restrict__ Aim,
                            const float2* __restrict__ binvg,
                            float2* __restrict__ qm) {
  int lj = blockIdx.y;
  int idx = blockIdx.x * 256 + threadIdx.x;
  int r = idx >> 7, c = idx & 127;
  const float* are = Are + (size_t)lj * 16384;
  const float* aim = Aim + (size_t)lj * 16384;
  const float2* binv = binvg + (size_t)lj * 16384;
  float2 acc = make_float2(0.f, 0.f);
  for (int k = 0; k < 128; ++k) {
    float re = are[r * 128 + k] + are[k * 128 + r];
    float im = aim[r * 128 + k] - aim[k * 128 + r];
    if (k == r) im -= 1.0f;
    float2 b = binv[k * 128 + c];
    acc.x += re * b.x - im * b.y;
    acc.y += re * b.y + im * b.x;
  }
  qm[(size_t)lj * 16384 + idx] = acc;
}

// ---------------- Gk = (RY*RX)^(kron 7) ----------------
__global__ void gk_kernel(const float* __restrict__ coeffs,
                          float2* __restrict__ gkm) {
  int lj = blockIdx.y;
  float a = coeffs[lj * 2 + 0], b = coeffs[lj * 2 + 1];
  float ca = cosf(0.5f * a), sa = sinf(0.5f * a);
  float cb = cosf(0.5f * b), sb = sinf(0.5f * b);
  float2 G[2][2];
  G[0][0] = make_float2(cb * ca, sb * sa);
  G[0][1] = make_float2(-sb * ca, -cb * sa);
  G[1][0] = make_float2(sb * ca, -cb * sa);
  G[1][1] = make_float2(cb * ca, -sb * sa);
  int idx = blockIdx.x * 256 + threadIdx.x;
  int r = idx >> 7, c = idx & 127;
  float2 acc = make_float2(1.f, 0.f);
#pragma unroll
  for (int bit = 6; bit >= 0; --bit) {
    float2 g = G[(r >> bit) & 1][(c >> bit) & 1];
    acc = make_float2(acc.x * g.x - acc.y * g.y, acc.x * g.y + acc.y * g.x);
  }
  gkm[(size_t)lj * 16384 + idx] = acc;
}

// ---------------- N_j[i][c] = sum_k q[k][i] * Gk[g[c]][k] ----------------
__global__ void nj_kernel(const float2* __restrict__ qm,
                          const float2* __restrict__ gkm,
                          const int* __restrict__ g,
                          float2* __restrict__ njm) {
  int lj = blockIdx.y;
  int idx = blockIdx.x * 256 + threadIdx.x;
  int i = idx >> 7, c = idx & 127;
  int gc = g[c];
  const float2* q = qm + (size_t)lj * 16384;
  const float2* gk = gkm + (size_t)lj * 16384;
  float2 acc = make_float2(0.f, 0.f);
  for (int k = 0; k < 128; ++k) {
    float2 qa = q[k * 128 + i];
    float2 gb = gk[gc * 128 + k];
    acc.x += qa.x * gb.x - qa.y * gb.y;
    acc.y += qa.x * gb.y + qa.y * gb.x;
  }
  njm[(size_t)lj * 16384 + idx] = acc;
}

// ---------------- U_l = N_{l,0} @ N_{l,1} ----------------
__global__ void compose_kernel(const float2* __restrict__ njm,
                               float2* __restrict__ um) {
  int l = blockIdx.y;
  int idx = blockIdx.x * 256 + threadIdx.x;
  int i = idx >> 7, c = idx & 127;
  const float2* n0 = njm + (size_t)(l * 2 + 0) * 16384;
  const float2* n1 = njm + (size_t)(l * 2 + 1) * 16384;
  float2 acc = make_float2(0.f, 0.f);
  for (int k = 0; k < 128; ++k) {
    float2 a = n0[i * 128 + k];
    float2 b = n1[k * 128 + c];
    acc.x += a.x * b.x - a.y * b.y;
    acc.y += a.x * b.y + a.y * b.x;
  }
  um[(size_t)l * 16384 + idx] = acc;
}

// ---------------- Wqd_l = Re(U_l) @ dec_w_l ----------------
__global__ void wqd_kernel(const float2* __restrict__ um,
                           const float* __restrict__ decw,
                           float* __restrict__ wqd) {
  int l = blockIdx.y;
  int idx = blockIdx.x * 256 + threadIdx.x;
  int i = idx >> 7, c = idx & 127;
  const float2* u = um + (size_t)l * 16384;
  const float* dw = decw + (size_t)l * 16384;
  float acc = 0.f;
  for (int k = 0; k < 128; ++k) acc += u[i * 128 + k].x * dw[k * 128 + c];
  wqd[(size_t)l * 16384 + idx] = acc;
}

// ==================== MFMA edge MLP: wave-owned 16-edge tiles ==============
// Swapped MFMA operands: mfma(W_frag, data_frag) -> each wave owns 16 edges x
// all 128 output cols. With the permuted weight-column layout, GEMM1's C regs
// ARE GEMM2's B-fragment after an in-register silu+bf16 pack: no LDS m1
// round-trip, no cross-lane shuffles, 3 barriers instead of 5, and af
// ds_reads drop 4x (each wave reads only its own 16 rows).
__global__ __launch_bounds__(256, 4) void edge_mfma_kernel(
    const ushort* __restrict__ hbf, const int* __restrict__ ei,
    const float* __restrict__ x, const float* __restrict__ ea,
    const int* __restrict__ elist, const int* __restrict__ cstart,
    const ushort* __restrict__ w1cs, const float* __restrict__ b1,
    const ushort* __restrict__ w2cs, const float* __restrict__ b2,
    float* __restrict__ agg, float* __restrict__ headp) {
  __shared__ ushort A[EPB * AS];      // A-tile; m2 (f32, 148/row) overlays rows
  __shared__ int rows[EPB];

  const int tid = threadIdx.x;
  const int lane = tid & 63, wave = tid >> 6;
  const int lrow = lane & 15, lq = lane >> 4;
  const int erow = wave * 16 + lrow;     // this lane's edge row in the tile

  const int i0 = blockIdx.x * EPB;
  {
    const int e = tid >> 2, j = tid & 3;   // wave w stages rows w*16..w*16+16
    const int edge = elist[i0 + e];
    const int r = ei[edge], c = ei[N_EDGES + edge];
    if (j == 0) rows[e] = r;
    const uint4* hr = (const uint4*)(hbf + (size_t)r * HDIM + j * 32);
    const uint4* hc = (const uint4*)(hbf + (size_t)c * HDIM + j * 32);
    uint4* d1 = (uint4*)(A + e * AS + j * 32);
    uint4* d2 = (uint4*)(A + e * AS + 128 + j * 32);
    d1[0] = hr[0]; d1[1] = hr[1]; d1[2] = hr[2]; d1[3] = hr[3];
    d2[0] = hc[0]; d2[1] = hc[1]; d2[2] = hc[2]; d2[3] = hc[3];
    if (j == 3) {
      float dx = x[r * 3 + 0] - x[c * 3 + 0];
      float dy = x[r * 3 + 1] - x[c * 3 + 1];
      float dz = x[r * 3 + 2] - x[c * 3 + 2];
      ushort* dst = A + e * AS;
      dst[256] = f2bf(dx * dx + dy * dy + dz * dz);
      dst[257] = f2bf(ea[edge]);
#pragma unroll
      for (int z = 258; z < 288; ++z) dst[z] = 0;
    }
  }
  __syncthreads();   // s1: A ready

  // ---- GEMM1: acc1[t] = W1_tile_t^T x A-rows (wave's 16 edges) ----
  f32x4 acc1[8];
#pragma unroll
  for (int t = 0; t < 8; ++t) acc1[t] = (f32x4){0.f, 0.f, 0.f, 0.f};
  {
    const ushort* wp = w1cs + lrow * 32 + lq * 8;
    const ushort* ap = A + erow * AS + lq * 8;
#pragma unroll
    for (int kt = 0; kt < 9; ++kt) {
      short8b af = *(const short8b*)(ap + kt * 32);
#pragma unroll
      for (int t = 0; t < 8; ++t) {
        short8b wf = *(const short8b*)(wp + kt * 4096 + t * 512);
        acc1[t] = __builtin_amdgcn_mfma_f32_16x16x32_bf16(wf, af, acc1[t], 0, 0, 0);
      }
    }
  }

  // ---- bias + silu + in-register pack: acc1 -> GEMM2 B-fragments ----
  short8b mf[4];
#pragma unroll
  for (int t = 0; t < 8; ++t) {
    const int nb = ((t >> 1) << 5) + (lq << 3) + ((t & 1) << 2);
    const float4 bb = *(const float4*)(b1 + nb);
    const int c = t >> 1, s = (t & 1) * 4;
    mf[c][s + 0] = (short)f2bf(silu_f(acc1[t][0] + bb.x));
    mf[c][s + 1] = (short)f2bf(silu_f(acc1[t][1] + bb.y));
    mf[c][s + 2] = (short)f2bf(silu_f(acc1[t][2] + bb.z));
    mf[c][s + 3] = (short)f2bf(silu_f(acc1[t][3] + bb.w));
  }
  __syncthreads();   // s2: all A reads done (m2 overlays A)

  // ---- GEMM2: acc2[t] = W2_tile_t^T x m1 (B-frag from registers) ----
  f32x4 acc2[8];
#pragma unroll
  for (int t = 0; t < 8; ++t) acc2[t] = (f32x4){0.f, 0.f, 0.f, 0.f};
  {
    const ushort* wp = w2cs + lrow * 32 + lq * 8;
#pragma unroll
    for (int kt = 0; kt < 4; ++kt) {
#pragma unroll
      for (int t = 0; t < 8; ++t) {
        short8b wf = *(const short8b*)(wp + kt * 4096 + t * 512);
        acc2[t] = __builtin_amdgcn_mfma_f32_16x16x32_bf16(wf, mf[kt], acc2[t], 0, 0, 0);
      }
    }
  }

  // ---- bias + silu -> m2 (f32) vector writes over own A rows ----
  {
    float* m2w = (float*)A;
#pragma unroll
    for (int t = 0; t < 8; ++t) {
      const int nb = ((t >> 1) << 5) + (lq << 3) + ((t & 1) << 2);
      const float4 bb = *(const float4*)(b2 + nb);
      f32x4 v;
      v[0] = silu_f(acc2[t][0] + bb.x);
      v[1] = silu_f(acc2[t][1] + bb.y);
      v[2] = silu_f(acc2[t][2] + bb.z);
      v[3] = silu_f(acc2[t][3] + bb.w);
      *(f32x4*)(m2w + erow * 148 + nb) = v;
    }
  }
  __syncthreads();   // s3: m2 ready

  // ---- segmented reduce over sorted rows; plain stores, no atomics ----
  const float* m2 = (const float*)A;
  const int e2 = tid & 63, cg = tid >> 6, cb = cg * 32;
  const int r_e = rows[e2];
  const bool leader = (e2 == 0) || (rows[e2 - 1] != r_e);
  if (leader) {
    f32x4 sum[8];
#pragma unroll
    for (int q = 0; q < 8; ++q) sum[q] = *(const f32x4*)(m2 + e2 * 148 + cb + q * 4);
    int f = e2 + 1;
    while (f < EPB && rows[f] == r_e) {
#pragma unroll
      for (int q = 0; q < 8; ++q) sum[q] += *(const f32x4*)(m2 + f * 148 + cb + q * 4);
      ++f;
    }
    float* dst = (e2 == 0 && cstart[r_e] < i0)
                     ? headp + (size_t)blockIdx.x * HDIM + cb   // continuation
                     : agg + (size_t)r_e * HDIM + cb;           // sole writer
#pragma unroll
    for (int q = 0; q < 8; ++q) *(f32x4*)(dst + q * 4) = sum[q];
  }
}

// ==================== MFMA node update (folds headp) ====================
// Same swapped/wave-owned structure; RMSNorm reduced fully in-wave (2 shfl),
// vectorized float4/ushort4 output writes, no m1/nbuf LDS phases.
__global__ __launch_bounds__(256, 2) void node_mfma_kernel(
    float* __restrict__ out_h, const float* __restrict__ agg,
    const int* __restrict__ cstart, const int* __restrict__ cend,
    const float* __restrict__ headp,
    const ushort* __restrict__ enccs, const float* __restrict__ encb,
    const ushort* __restrict__ wqdcs, const float* __restrict__ decb,
    ushort* __restrict__ hbf) {
  __shared__ ushort A[EPB * NAS];
  const int tid = threadIdx.x;
  const int n0 = blockIdx.x * EPB;

  const int lane = tid & 63, wave = tid >> 6;
  const int lrow = lane & 15, lq = lane >> 4;
  const int erow = wave * 16 + lrow;

  {
    const int e = tid >> 2, j = tid & 3;
    int node = n0 + e;
    if (node >= N_NODES) node = N_NODES - 1;
    if (j < 2) {
      const float4* s4 = (const float4*)(out_h + (size_t)node * HDIM + j * 64);
      ushort* dst = A + e * NAS + j * 64;
#pragma unroll
      for (int i = 0; i < 16; ++i) {
        float4 v = s4[i];
        ushort4 o;
        o.x = f2bf(v.x); o.y = f2bf(v.y); o.z = f2bf(v.z); o.w = f2bf(v.w);
        ((ushort4*)dst)[i] = o;
      }
    } else {
      const int s = cstart[node], en = cend[node];
      const bool hasAgg = en > s;
      const float4* a4 = (const float4*)(agg + (size_t)node * HDIM + (j - 2) * 64);
      const int bb0 = (s >> 6) + 1;
      const int bb1 = hasAgg ? ((en - 1) >> 6) : 0;
      ushort* dst = A + e * NAS + 128 + (j - 2) * 64;
#pragma unroll
      for (int i = 0; i < 16; ++i) {
        float4 v = hasAgg ? a4[i] : make_float4(0.f, 0.f, 0.f, 0.f);
        for (int bb = bb0; bb <= bb1; ++bb) {
          float4 hv = *(const float4*)(headp + (size_t)bb * HDIM + (j - 2) * 64 + i * 4);
          v.x += hv.x; v.y += hv.y; v.z += hv.z; v.w += hv.w;
        }
        ushort4 o;
        o.x = f2bf(v.x * 0.01f); o.y = f2bf(v.y * 0.01f);
        o.z = f2bf(v.z * 0.01f); o.w = f2bf(v.w * 0.01f);
        ((ushort4*)dst)[i] = o;
      }
    }
  }
  __syncthreads();

  // ---- GEMM1: q_in tiles ----
  f32x4 acc[8];
#pragma unroll
  for (int t = 0; t < 8; ++t) acc[t] = (f32x4){0.f, 0.f, 0.f, 0.f};
  {
    const ushort* wp = enccs + lrow * 32 + lq * 8;
    const ushort* ap = A + erow * NAS + lq * 8;
#pragma unroll
    for (int kt = 0; kt < 8; ++kt) {
      short8b af = *(const short8b*)(ap + kt * 32);
#pragma unroll
      for (int t = 0; t < 8; ++t) {
        short8b wf = *(const short8b*)(wp + kt * 4096 + t * 512);
        acc[t] = __builtin_amdgcn_mfma_f32_16x16x32_bf16(wf, af, acc[t], 0, 0, 0);
      }
    }
  }

  // ---- bias + in-wave sum of squares (lane has 32 of 128 dims) ----
  float q[8][4];
  float ss = 0.f;
#pragma unroll
  for (int t = 0; t < 8; ++t) {
    const int nb = ((t >> 1) << 5) + (lq << 3) + ((t & 1) << 2);
    const float4 bb = *(const float4*)(encb + nb);
    q[t][0] = acc[t][0] + bb.x;
    q[t][1] = acc[t][1] + bb.y;
    q[t][2] = acc[t][2] + bb.z;
    q[t][3] = acc[t][3] + bb.w;
    ss += q[t][0] * q[t][0] + q[t][1] * q[t][1] + q[t][2] * q[t][2] + q[t][3] * q[t][3];
  }
  ss += __shfl_xor(ss, 16, 64);
  ss += __shfl_xor(ss, 32, 64);
  const float inv = 1.0f / sqrtf(ss + 1e-12f);

  short8b mf[4];
#pragma unroll
  for (int t = 0; t < 8; ++t) {
    const int c = t >> 1, s = (t & 1) * 4;
    mf[c][s + 0] = (short)f2bf(q[t][0] * inv);
    mf[c][s + 1] = (short)f2bf(q[t][1] * inv);
    mf[c][s + 2] = (short)f2bf(q[t][2] * inv);
    mf[c][s + 3] = (short)f2bf(q[t][3] * inv);
  }

  // ---- GEMM2: wqd ----
  f32x4 acc2[8];
#pragma unroll
  for (int t = 0; t < 8; ++t) acc2[t] = (f32x4){0.f, 0.f, 0.f, 0.f};
  {
    const ushort* wp = wqdcs + lrow * 32 + lq * 8;
#pragma unroll
    for (int kt = 0; kt < 4; ++kt) {
#pragma unroll
      for (int t = 0; t < 8; ++t) {
        short8b wf = *(const short8b*)(wp + kt * 4096 + t * 512);
        acc2[t] = __builtin_amdgcn_mfma_f32_16x16x32_bf16(wf, mf[kt], acc2[t], 0, 0, 0);
      }
    }
  }

  // ---- h += dec(qs) + dec_b : vectorized RMW, lane owns 32 of 128 cols ----
  const int node = n0 + erow;
  if (node < N_NODES) {
#pragma unroll
    for (int t = 0; t < 8; ++t) {
      const int nb = ((t >> 1) << 5) + (lq << 3) + ((t & 1) << 2);
      const float4 db = *(const float4*)(decb + nb);
      const size_t off = (size_t)node * HDIM + nb;
      float4 o = *(const float4*)(out_h + off);
      float4 hn;
      hn.x = o.x + acc2[t][0] + db.x;
      hn.y = o.y + acc2[t][1] + db.y;
      hn.z = o.z + acc2[t][2] + db.z;
      hn.w = o.w + acc2[t][3] + db.w;
      *(float4*)(out_h + off) = hn;
      ushort4 ob;
      ob.x = f2bf(hn.x); ob.y = f2bf(hn.y); ob.z = f2bf(hn.z); ob.w = f2bf(hn.w);
      *(ushort4*)(hbf + off) = ob;
    }
  }
}

// ==================== MFMA coordinate head ===============
// Swapped structure; t-scalar per edge reduced fully in-register (2 shfl),
// no m2/pbuf LDS phases. 2 barriers total.
__global__ __launch_bounds__(256, 4) void coord_mfma_kernel(
    const ushort* __restrict__ hbf, const int* __restrict__ ei,
    const float* __restrict__ x, const float* __restrict__ ea,
    const int* __restrict__ elist,
    const ushort* __restrict__ w1cs, const float* __restrict__ b1,
    const ushort* __restrict__ w2cs, const float* __restrict__ b2,
    const float* __restrict__ w3, float* __restrict__ xout) {
  __shared__ ushort A[EPB * AS];
  __shared__ int rows[EPB];
  __shared__ int colsA[EPB];
  __shared__ float tv[EPB];

  const int tid = threadIdx.x;
  const int lane = tid & 63, wave = tid >> 6;
  const int lrow = lane & 15, lq = lane >> 4;
  const int erow = wave * 16 + lrow;

  const int i0 = blockIdx.x * EPB;
  {
    const int e = tid >> 2, j = tid & 3;
    const int edge = elist[i0 + e];
    const int r = ei[edge], c = ei[N_EDGES + edge];
    if (j == 0) { rows[e] = r; colsA[e] = c; }
    const uint4* hr = (const uint4*)(hbf + (size_t)r * HDIM + j * 32);
    const uint4* hc = (const uint4*)(hbf + (size_t)c * HDIM + j * 32);
    uint4* d1 = (uint4*)(A + e * AS + j * 32);
    uint4* d2 = (uint4*)(A + e * AS + 128 + j * 32);
    d1[0] = hr[0]; d1[1] = hr[1]; d1[2] = hr[2]; d1[3] = hr[3];
    d2[0] = hc[0]; d2[1] = hc[1]; d2[2] = hc[2]; d2[3] = hc[3];
    if (j == 3) {
      float dx = x[r * 3 + 0] - x[c * 3 + 0];
      float dy = x[r * 3 + 1] - x[c * 3 + 1];
      float dz = x[r * 3 + 2] - x[c * 3 + 2];
      ushort* dst = A + e * AS;
      dst[256] = f2bf(dx * dx + dy * dy + dz * dz);
      dst[257] = f2bf(ea[edge]);
#pragma unroll
      for (int z = 258; z < 288; ++z) dst[z] = 0;
    }
  }
  __syncthreads();   // s1: A ready

  f32x4 acc1[8];
#pragma unroll
  for (int t = 0; t < 8; ++t) acc1[t] = (f32x4){0.f, 0.f, 0.f, 0.f};
  {
    const ushort* wp = w1cs + lrow * 32 + lq * 8;
    const ushort* ap = A + erow * AS + lq * 8;
#pragma unroll
    for (int kt = 0; kt < 9; ++kt) {
      short8b af = *(const short8b*)(ap + kt * 32);
#pragma unroll
      for (int t = 0; t < 8; ++t) {
        short8b wf = *(const short8b*)(wp + kt * 4096 + t * 512);
        acc1[t] = __builtin_amdgcn_mfma_f32_16x16x32_bf16(wf, af, acc1[t], 0, 0, 0);
      }
    }
  }

  short8b mf[4];
#pragma unroll
  for (int t = 0; t < 8; ++t) {
    const int nb = ((t >> 1) << 5) + (lq << 3) + ((t & 1) << 2);
    const float4 bb = *(const float4*)(b1 + nb);
    const int c = t >> 1, s = (t & 1) * 4;
    mf[c][s + 0] = (short)f2bf(silu_f(acc1[t][0] + bb.x));
    mf[c][s + 1] = (short)f2bf(silu_f(acc1[t][1] + bb.y));
    mf[c][s + 2] = (short)f2bf(silu_f(acc1[t][2] + bb.z));
    mf[c][s + 3] = (short)f2bf(silu_f(acc1[t][3] + bb.w));
  }

  f32x4 acc2[8];
#pragma unroll
  for (int t = 0; t < 8; ++t) acc2[t] = (f32x4){0.f, 0.f, 0.f, 0.f};
  {
    const ushort* wp = w2cs + lrow * 32 + lq * 8;
#pragma unroll
    for (int kt = 0; kt < 4; ++kt) {
#pragma unroll
      for (int t = 0; t < 8; ++t) {
        short8b wf = *(const short8b*)(wp + kt * 4096 + t * 512);
        acc2[t] = __builtin_amdgcn_mfma_f32_16x16x32_bf16(wf, mf[kt], acc2[t], 0, 0, 0);
      }
    }
  }

  // ---- t-scalar: per-lane partial over its 32 cols, reduce across lq ----
  float tpart = 0.f;
#pragma unroll
  for (int t = 0; t < 8; ++t) {
    const int nb = ((t >> 1) << 5) + (lq << 3) + ((t & 1) << 2);
    const float4 bb = *(const float4*)(b2 + nb);
    const float4 wf = *(const float4*)(w3 + nb);
    tpart += silu_f(acc2[t][0] + bb.x) * wf.x;
    tpart += silu_f(acc2[t][1] + bb.y) * wf.y;
    tpart += silu_f(acc2[t][2] + bb.z) * wf.z;
    tpart += silu_f(acc2[t][3] + bb.w) * wf.w;
  }
  tpart += __shfl_xor(tpart, 16, 64);
  tpart += __shfl_xor(tpart, 32, 64);
  if (lq == 0) tv[erow] = tpart * 0.01f;
  __syncthreads();   // s2: tv ready

  if (tid < EPB) {
    const int e = tid;
    const int r_e = rows[e];
    const bool leader = (e == 0) || (rows[e - 1] != r_e);
    if (leader) {
      float sx = 0.f, sy = 0.f, sz = 0.f;
      int f = e;
      do {
        const int c = colsA[f];
        float dx = x[r_e * 3 + 0] - x[c * 3 + 0];
        float dy = x[r_e * 3 + 1] - x[c * 3 + 1];
        float dz = x[r_e * 3 + 2] - x[c * 3 + 2];
        float radial = dx * dx + dy * dy + dz * dz;
        float s = 1.0f / (sqrtf(radial + 1e-8f) + 1.0f);
        float t = tv[f];
        sx += dx * s * t; sy += dy * s * t; sz += dz * s * t;
        ++f;
      } while (f < EPB && rows[f] == r_e);
      atomicAdd(&xout[r_e * 3 + 0], sx);
      atomicAdd(&xout[r_e * 3 + 1], sy);
      atomicAdd(&xout[r_e * 3 + 2], sz);
    }
  }
}

extern "C" void kernel_launch(void* const* d_in, const int* in_sizes, int n_in,
                              void* d_out, int out_size, void* d_ws, size_t ws_size,
                              hipStream_t stream) {
  const float* h     = (const float*)d_in[0];
  const float* x     = (const float*)d_in[1];
  const int*   ei    = (const int*)d_in[2];
  const float* ea    = (const float*)d_in[3];
  const float* e_w1  = (const float*)d_in[4];
  const float* e_b1  = (const float*)d_in[5];
  const float* e_w2  = (const float*)d_in[6];
  const float* e_b2  = (const float*)d_in[7];
  const float* enc_w = (const float*)d_in[8];
  const float* enc_b = (const float*)d_in[9];
  const float* coeffs= (const float*)d_in[10];
  const float* A_re  = (const float*)d_in[11];
  const float* A_im  = (const float*)d_in[12];
  const float* dec_w = (const float*)d_in[13];
  const float* dec_b = (const float*)d_in[14];
  const float* c_w1  = (const float*)d_in[15];
  const float* c_b1  = (const float*)d_in[16];
  const float* c_w2  = (const float*)d_in[17];
  const float* c_b2  = (const float*)d_in[18];
  const float* c_w3  = (const float*)d_in[19];

  float* out = (float*)d_out;
  float* ws  = (float*)d_ws;

  // workspace layout (float offsets) — ~33.1 MB
  float*  agg    = ws;                          // 3,840,000
  float2* xa     = (float2*)(ws + 3840000);     // 131,072 f
  float2* xb     = (float2*)(ws + 3971072);     // 131,072 f
  float2* xt     = (float2*)(ws + 4102144);     // 131,072 f
  float2* qm     = (float2*)(ws + 4233216);     // 131,072 f
  float2* gkm    = (float2*)(ws + 4364288);     // 131,072 f
  float2* njm    = (float2*)(ws + 4495360);     // 131,072 f
  float2* um     = (float2*)(ws + 4626432);     //  65,536 f
  float*  wqd    = ws + 4691968;                //  32,768 f
  int*    perm   = (int*)(ws + 4724736);        //     128
  int*    cursor = (int*)(ws + 4724864);        //  30,000 (post-fill: CSR ends)
  int*    cstart = (int*)(ws + 4754864);        //  30,000 (CSR starts)
  int*    elist  = (int*)(ws + 4784864);        // 480,000
  float*  headp  = ws + 5264864;                // 7500*128 = 960,000
  ushort* hbf    = (ushort*)(ws + 6224864);     // 1,920,000 f
  ushort* w1cs   = (ushort*)(ws + 8144864);
  ushort* w2cs   = (ushort*)(ws + 8181728);
  ushort* cw1cs  = (ushort*)(ws + 8198112);
  ushort* cw2cs  = (ushort*)(ws + 8216544);
  ushort* enccs  = (ushort*)(ws + 8224736);
  ushort* wqdcs  = (ushort*)(ws + 8257504);

  init_out_kernel<<<15000, 256, 0, stream>>>(h, x, out);

  // counting sort of edges by destination row (cstart kept immutable)
  hipMemsetAsync(cursor, 0, N_NODES * sizeof(int), stream);
  count_kernel<<<1875, 256, 0, stream>>>(ei, cursor);
  scan_kernel<<<1, 1024, 0, stream>>>(cursor, cstart);
  fill_kernel<<<1875, 256, 0, stream>>>(ei, cursor, elist);

  // quantum-operator precompute: Newton-Schulz inverse + tiny GEMM chain
  perm_kernel<<<1, 128, 0, stream>>>(perm);
  ns_init_kernel<<<dim3(64, 4), 256, 0, stream>>>(A_re, A_im, xa);
  float2* cur = xa;
  float2* nxt = xb;
  for (int it = 0; it < 4; ++it) {
    ns_bx_kernel<<<dim3(64, 4), 256, 0, stream>>>(A_re, A_im, cur, xt);
    ns_upd_kernel<<<dim3(64, 4), 256, 0, stream>>>(cur, xt, nxt);
    float2* tmp = cur; cur = nxt; nxt = tmp;
  }
  qmat_kernel<<<dim3(64, 4), 256, 0, stream>>>(A_re, A_im, cur, qm);
  gk_kernel<<<dim3(64, 4), 256, 0, stream>>>(coeffs, gkm);
  nj_kernel<<<dim3(64, 4), 256, 0, stream>>>(qm, gkm, perm, njm);
  compose_kernel<<<dim3(64, 2), 256, 0, stream>>>(njm, um);
  wqd_kernel<<<dim3(64, 2), 256, 0, stream>>>(um, dec_w, wqd);

  // weight conversions to chunked bf16 [kt][p][kk] with permuted columns
  for (int l = 0; l < 2; ++l) {
    convert_w_kernel<<<144, 256, 0, stream>>>(e_w1 + (size_t)l * 258 * HDIM,
                                              w1cs + (size_t)l * 9 * 4096, 258, 9);
    convert_w_kernel<<<64, 256, 0, stream>>>(e_w2 + (size_t)l * HDIM * HDIM,
                                             w2cs + (size_t)l * 4 * 4096, 128, 4);
    convert_w_kernel<<<128, 256, 0, stream>>>(enc_w + (size_t)l * 256 * HDIM,
                                              enccs + (size_t)l * 8 * 4096, 256, 8);
    convert_w_kernel<<<64, 256, 0, stream>>>(wqd + (size_t)l * HDIM * HDIM,
                                             wqdcs + (size_t)l * 4 * 4096, 128, 4);
  }
  convert_w_kernel<<<144, 256, 0, stream>>>(c_w1, cw1cs, 258, 9);
  convert_w_kernel<<<64, 256, 0, stream>>>(c_w2, cw2cs, 128, 4);

  // initial bf16 h
  h_to_bf_kernel<<<3750, 256, 0, stream>>>(out, hbf);

  // two message-passing layers
  for (int l = 0; l < 2; ++l) {
    edge_mfma_kernel<<<N_EDGES / EPB, 256, 0, stream>>>(
        hbf, ei, x, ea, elist, cstart,
        w1cs + (size_t)l * 9 * 4096, e_b1 + l * HDIM,
        w2cs + (size_t)l * 4 * 4096, e_b2 + l * HDIM, agg, headp);
    node_mfma_kernel<<<(N_NODES + EPB - 1) / EPB, 256, 0, stream>>>(
        out, agg, cstart, cursor, headp,
        enccs + (size_t)l * 8 * 4096, enc_b + l * HDIM,
        wqdcs + (size_t)l * 4 * 4096, dec_b + l * HDIM, hbf);
  }

  // coordinate head
  coord_mfma_kernel<<<N_EDGES / EPB, 256, 0, stream>>>(
      hbf, ei, x, ea, elist, cw1cs, c_b1, cw2cs, c_b2, c_w3,
      out + (size_t)N_NODES * HDIM);
}

// Round 2
// 1039.800 us; speedup vs baseline: 1.0715x; 1.0715x over previous
//
#include <hip/hip_runtime.h>
#include <math.h>

#define N_NODES 30000
#define N_EDGES 480000
#define HDIM 128
#define EPB 128       // edges per MFMA block (4 waves x 32 edges); max node
                      // degree (~40) < EPB so a CSR range spans <=2 blocks.
#define NPB 64        // nodes per block in node kernel
#define AS 296        // edge A-tile row stride (ushort) = 592 B = 148 f32
#define NAS 264       // node A-tile row stride (ushort)

typedef __attribute__((ext_vector_type(8))) short short8b;
typedef __attribute__((ext_vector_type(4))) float f32x4;

__device__ __forceinline__ float silu_f(float v) {
  return v / (1.0f + __expf(-v));
}

__device__ __forceinline__ unsigned short f2bf(float f) {
  unsigned int u = __float_as_uint(f);
  unsigned int r = u + 0x7fffu + ((u >> 16) & 1u);
  return (unsigned short)(r >> 16);
}

// ---------------- output init: out = [h | x] ----------------
__global__ void init_out_kernel(const float* __restrict__ h,
                                const float* __restrict__ x,
                                float* __restrict__ out) {
  int idx = blockIdx.x * 256 + threadIdx.x;
  out[idx] = h[idx];
  if (idx < N_NODES * 3) out[N_NODES * HDIM + idx] = x[idx];
}

// ---------------- h (fp32) -> hbf (bf16) ----------------
__global__ void h_to_bf_kernel(const float* __restrict__ h,
                               ushort* __restrict__ hbf) {
  int idx = blockIdx.x * 256 + threadIdx.x;
  float4 v = ((const float4*)h)[idx];
  ushort4 o;
  o.x = f2bf(v.x); o.y = f2bf(v.y); o.z = f2bf(v.z); o.w = f2bf(v.w);
  ((ushort4*)hbf)[idx] = o;
}

// ---------------- weight convert: W[K][128] fp32 -> [KT][128][32] bf16 ----
// Column order is PERMUTED so that the MFMA C-layout of output tiles 2c,2c+1
// directly forms the B-fragment (8 consecutive k at lq*8) of the next GEMM:
//   tile row p (0..127) holds true column
//   n = (p>>5)*32 + ((p>>2)&3)*8 + ((p>>4)&1)*4 + (p&3)     (bijective)
// Biases and output writes use the matching base nb(t) = (t>>1)*32+lq*8+(t&1)*4.
__global__ void convert_w_kernel(const float* __restrict__ W,
                                 ushort* __restrict__ dst, int Kreal, int KT) {
  int idx = blockIdx.x * 256 + threadIdx.x;
  if (idx >= KT * 4096) return;
  int kt = idx >> 12, rem = idx & 4095, p = rem >> 5, kk = rem & 31;
  int n = ((p >> 5) << 5) | (((p >> 2) & 3) << 3) | (((p >> 4) & 1) << 2) | (p & 3);
  int k = kt * 32 + kk;
  float v = (k < Kreal) ? W[(size_t)k * HDIM + n] : 0.0f;
  dst[idx] = f2bf(v);
}

// ---------------- counting sort of edges by destination row ----------------
__global__ void count_kernel(const int* __restrict__ ei, int* __restrict__ cursor) {
  int e = blockIdx.x * 256 + threadIdx.x;
  atomicAdd(&cursor[ei[e]], 1);
}

__global__ __launch_bounds__(1024) void scan_kernel(int* __restrict__ cursor,
                                                    int* __restrict__ cstart) {
  __shared__ int sums[1024];
  const int tid = threadIdx.x;
  const int base = tid * 30;
  int local[30];
  int s = 0;
#pragma unroll
  for (int j = 0; j < 30; ++j) {
    int idx = base + j;
    int d = (idx < N_NODES) ? cursor[idx] : 0;
    local[j] = s;
    s += d;
  }
  sums[tid] = s;
  __syncthreads();
  for (int off = 1; off < 1024; off <<= 1) {
    int add = (tid >= off) ? sums[tid - off] : 0;
    __syncthreads();
    sums[tid] += add;
    __syncthreads();
  }
  int excl = (tid == 0) ? 0 : sums[tid - 1];
#pragma unroll
  for (int j = 0; j < 30; ++j) {
    int idx = base + j;
    if (idx < N_NODES) {
      int v = excl + local[j];
      cursor[idx] = v;
      cstart[idx] = v;   // immutable CSR starts (cursor mutates in fill)
    }
  }
}

__global__ void fill_kernel(const int* __restrict__ ei, int* __restrict__ cursor,
                            int* __restrict__ elist) {
  int e = blockIdx.x * 256 + threadIdx.x;
  int r = ei[e];
  int pos = atomicAdd(&cursor[r], 1);   // after this kernel cursor[n] = CSR end
  elist[pos] = e;
}

// ---------------- CNOT ring permutation ----------------
__global__ void perm_kernel(int* __restrict__ g) {
  int i = threadIdx.x;
  int v = i;
  const int cs[7] = {6, 5, 4, 3, 2, 1, 0};
  const int ts[7] = {0, 6, 5, 4, 3, 2, 1};
#pragma unroll
  for (int p = 0; p < 7; ++p) {
    int cb = (v >> (6 - cs[p])) & 1;
    v = v ^ (cb << (6 - ts[p]));
  }
  g[i] = v;
}

// ============ Newton-Schulz inverse of B = A_h + iI ============
__global__ void ns_init_kernel(const float* __restrict__ Are,
                               const float* __restrict__ Aim,
                               float2* __restrict__ X) {
  int lj = blockIdx.y;
  int idx = blockIdx.x * 256 + threadIdx.x;
  int r = idx >> 7, c = idx & 127;
  const float* are = Are + (size_t)lj * 16384;
  const float* aim = Aim + (size_t)lj * 16384;
  float re = are[r * 128 + c] + are[c * 128 + r];
  float im = aim[r * 128 + c] - aim[c * 128 + r];
  if (r == c) im -= 1.0f;
  X[(size_t)lj * 16384 + idx] = make_float2(re, im);
}

__global__ void ns_bx_kernel(const float* __restrict__ Are,
                             const float* __restrict__ Aim,
                             const float2* __restrict__ X,
                             float2* __restrict__ T) {
  int lj = blockIdx.y;
  int idx = blockIdx.x * 256 + threadIdx.x;
  int r = idx >> 7, c = idx & 127;
  const float* are = Are + (size_t)lj * 16384;
  const float* aim = Aim + (size_t)lj * 16384;
  const float2* x = X + (size_t)lj * 16384;
  float2 acc = make_float2(0.f, 0.f);
  for (int k = 0; k < 128; ++k) {
    float re = are[r * 128 + k] + are[k * 128 + r];
    float im = aim[r * 128 + k] - aim[k * 128 + r];
    if (k == r) im += 1.0f;
    float2 b = x[k * 128 + c];
    acc.x += re * b.x - im * b.y;
    acc.y += re * b.y + im * b.x;
  }
  T[(size_t)lj * 16384 + idx] = acc;
}

__global__ void ns_upd_kernel(const float2* __restrict__ X,
                              const float2* __restrict__ T,
                              float2* __restrict__ Xn) {
  int lj = blockIdx.y;
  int idx = blockIdx.x * 256 + threadIdx.x;
  int r = idx >> 7, c = idx & 127;
  const float2* x = X + (size_t)lj * 16384;
  const float2* t = T + (size_t)lj * 16384;
  float2 acc = make_float2(0.f, 0.f);
  for (int k = 0; k < 128; ++k) {
    float2 a = x[r * 128 + k];
    float2 b = t[k * 128 + c];
    acc.x += a.x * b.x - a.y * b.y;
    acc.y += a.x * b.y + a.y * b.x;
  }
  float2 xc = x[r * 128 + c];
  Xn[(size_t)lj * 16384 + idx] = make_float2(2.f * xc.x - acc.x, 2.f * xc.y - acc.y);
}

// ---------------- q = (A_h - iI) * Binv ----------------
__global__ void qmat_kernel(const float* __restrict__ Are,
                            const float* __restrict__ Aim,
                            const float2* __restrict__ binvg,
                            float2* __restrict__ qm) {
  int lj = blockIdx.y;
  int idx = blockIdx.x * 256 + threadIdx.x;
  int r = idx >> 7, c = idx & 127;
  const float* are = Are + (size_t)lj * 16384;
  const float* aim = Aim + (size_t)lj * 16384;
  const float2* binv = binvg + (size_t)lj * 16384;
  float2 acc = make_float2(0.f, 0.f);
  for (int k = 0; k < 128; ++k) {
    float re = are[r * 128 + k] + are[k * 128 + r];
    float im = aim[r * 128 + k] - aim[k * 128 + r];
    if (k == r) im -= 1.0f;
    float2 b = binv[k * 128 + c];
    acc.x += re * b.x - im * b.y;
    acc.y += re * b.y + im * b.x;
  }
  qm[(size_t)lj * 16384 + idx] = acc;
}

// ---------------- Gk = (RY*RX)^(kron 7) ----------------
__global__ void gk_kernel(const float* __restrict__ coeffs,
                          float2* __restrict__ gkm) {
  int lj = blockIdx.y;
  float a = coeffs[lj * 2 + 0], b = coeffs[lj * 2 + 1];
  float ca = cosf(0.5f * a), sa = sinf(0.5f * a);
  float cb = cosf(0.5f * b), sb = sinf(0.5f * b);
  float2 G[2][2];
  G[0][0] = make_float2(cb * ca, sb * sa);
  G[0][1] = make_float2(-sb * ca, -cb * sa);
  G[1][0] = make_float2(sb * ca, -cb * sa);
  G[1][1] = make_float2(cb * ca, -sb * sa);
  int idx = blockIdx.x * 256 + threadIdx.x;
  int r = idx >> 7, c = idx & 127;
  float2 acc = make_float2(1.f, 0.f);
#pragma unroll
  for (int bit = 6; bit >= 0; --bit) {
    float2 g = G[(r >> bit) & 1][(c >> bit) & 1];
    acc = make_float2(acc.x * g.x - acc.y * g.y, acc.x * g.y + acc.y * g.x);
  }
  gkm[(size_t)lj * 16384 + idx] = acc;
}

// ---------------- N_j[i][c] = sum_k q[k][i] * Gk[g[c]][k] ----------------
__global__ void nj_kernel(const float2* __restrict__ qm,
                          const float2* __restrict__ gkm,
                          const int* __restrict__ g,
                          float2* __restrict__ njm) {
  int lj = blockIdx.y;
  int idx = blockIdx.x * 256 + threadIdx.x;
  int i = idx >> 7, c = idx & 127;
  int gc = g[c];
  const float2* q = qm + (size_t)lj * 16384;
  const float2* gk = gkm + (size_t)lj * 16384;
  float2 acc = make_float2(0.f, 0.f);
  for (int k = 0; k < 128; ++k) {
    float2 qa = q[k * 128 + i];
    float2 gb = gk[gc * 128 + k];
    acc.x += qa.x * gb.x - qa.y * gb.y;
    acc.y += qa.x * gb.y + qa.y * gb.x;
  }
  njm[(size_t)lj * 16384 + idx] = acc;
}

// ---------------- U_l = N_{l,0} @ N_{l,1} ----------------
__global__ void compose_kernel(const float2* __restrict__ njm,
                               float2* __restrict__ um) {
  int l = blockIdx.y;
  int idx = blockIdx.x * 256 + threadIdx.x;
  int i = idx >> 7, c = idx & 127;
  const float2* n0 = njm + (size_t)(l * 2 + 0) * 16384;
  const float2* n1 = njm + (size_t)(l * 2 + 1) * 16384;
  float2 acc = make_float2(0.f, 0.f);
  for (int k = 0; k < 128; ++k) {
    float2 a = n0[i * 128 + k];
    float2 b = n1[k * 128 + c];
    acc.x += a.x * b.x - a.y * b.y;
    acc.y += a.x * b.y + a.y * b.x;
  }
  um[(size_t)l * 16384 + idx] = acc;
}

// ---------------- Wqd_l = Re(U_l) @ dec_w_l ----------------
__global__ void wqd_kernel(const float2* __restrict__ um,
                           const float* __restrict__ decw,
                           float* __restrict__ wqd) {
  int l = blockIdx.y;
  int idx = blockIdx.x * 256 + threadIdx.x;
  int i = idx >> 7, c = idx & 127;
  const float2* u = um + (size_t)l * 16384;
  const float* dw = decw + (size_t)l * 16384;
  float acc = 0.f;
  for (int k = 0; k < 128; ++k) acc += u[i * 128 + k].x * dw[k * 128 + c];
  wqd[(size_t)l * 16384 + idx] = acc;
}

// ==================== MFMA edge MLP ========================================
// Swapped operands (wave owns edges on lrow axis, in-register GEMM1->GEMM2
// chain via permuted weight columns) + two fixes for round-1's regression:
//  - EPB=128, 32 edges/wave: 2 B-frags per weight frag -> MFMA:wload = 2:1,
//    and L1 captures the 4-wave reuse of each 8KB chunk (L2 traffic /8).
//  - explicit 1-kt-deep register prefetch of the 8 weight fragments; VGPR
//    cap lifted via launch_bounds(256,2) (LDS 76KB -> 2 blocks/CU anyway).
__global__ __launch_bounds__(256, 2) void edge_mfma_kernel(
    const ushort* __restrict__ hbf, const int* __restrict__ ei,
    const float* __restrict__ x, const float* __restrict__ ea,
    const int* __restrict__ elist, const int* __restrict__ cstart,
    const ushort* __restrict__ w1cs, const float* __restrict__ b1,
    const ushort* __restrict__ w2cs, const float* __restrict__ b2,
    float* __restrict__ agg, float* __restrict__ headp) {
  __shared__ ushort A[EPB * AS];      // 75,776B; m2 f32 [128][148] overlays
  __shared__ int rows[EPB];

  const int tid = threadIdx.x;
  const int lane = tid & 63, wave = tid >> 6;
  const int lrow = lane & 15, lq = lane >> 4;
  const int erow0 = wave * 32 + lrow;    // lane's two edge rows
  const int erow1 = erow0 + 16;

  const int i0 = blockIdx.x * EPB;
#pragma unroll
  for (int it = 0; it < 2; ++it) {
    const int e = it * 64 + (tid >> 2), j = tid & 3;
    const int edge = elist[i0 + e];
    const int r = ei[edge], c = ei[N_EDGES + edge];
    if (j == 0) rows[e] = r;
    const uint4* hr = (const uint4*)(hbf + (size_t)r * HDIM + j * 32);
    const uint4* hc = (const uint4*)(hbf + (size_t)c * HDIM + j * 32);
    uint4* d1 = (uint4*)(A + e * AS + j * 32);
    uint4* d2 = (uint4*)(A + e * AS + 128 + j * 32);
    d1[0] = hr[0]; d1[1] = hr[1]; d1[2] = hr[2]; d1[3] = hr[3];
    d2[0] = hc[0]; d2[1] = hc[1]; d2[2] = hc[2]; d2[3] = hc[3];
    if (j == 3) {
      float dx = x[r * 3 + 0] - x[c * 3 + 0];
      float dy = x[r * 3 + 1] - x[c * 3 + 1];
      float dz = x[r * 3 + 2] - x[c * 3 + 2];
      ushort* dst = A + e * AS;
      dst[256] = f2bf(dx * dx + dy * dy + dz * dz);
      dst[257] = f2bf(ea[edge]);
#pragma unroll
      for (int z = 258; z < 288; ++z) dst[z] = 0;
    }
  }
  __syncthreads();   // s1: A ready

  // ---- GEMM1: acc1[t][eg] = W1_tile_t^T x A-rows (wave's 32 edges) ----
  f32x4 acc1[8][2];
#pragma unroll
  for (int t = 0; t < 8; ++t)
#pragma unroll
    for (int eg = 0; eg < 2; ++eg) acc1[t][eg] = (f32x4){0.f, 0.f, 0.f, 0.f};
  {
    const ushort* wp = w1cs + lrow * 32 + lq * 8;
    const ushort* ap0 = A + erow0 * AS + lq * 8;
    const ushort* ap1 = A + erow1 * AS + lq * 8;
    short8b wc[8];
#pragma unroll
    for (int t = 0; t < 8; ++t) wc[t] = *(const short8b*)(wp + t * 512);
#pragma unroll
    for (int kt = 0; kt < 9; ++kt) {
      short8b wn[8];
      if (kt < 8) {
#pragma unroll
        for (int t = 0; t < 8; ++t)
          wn[t] = *(const short8b*)(wp + (kt + 1) * 4096 + t * 512);
      }
      short8b af0 = *(const short8b*)(ap0 + kt * 32);
      short8b af1 = *(const short8b*)(ap1 + kt * 32);
#pragma unroll
      for (int t = 0; t < 8; ++t) {
        acc1[t][0] = __builtin_amdgcn_mfma_f32_16x16x32_bf16(wc[t], af0, acc1[t][0], 0, 0, 0);
        acc1[t][1] = __builtin_amdgcn_mfma_f32_16x16x32_bf16(wc[t], af1, acc1[t][1], 0, 0, 0);
      }
      if (kt < 8) {
#pragma unroll
        for (int t = 0; t < 8; ++t) wc[t] = wn[t];
      }
    }
  }

  // ---- bias + silu + in-register pack: acc1 -> GEMM2 B-fragments ----
  short8b mf[4][2];
#pragma unroll
  for (int t = 0; t < 8; ++t) {
    const int nb = ((t >> 1) << 5) + (lq << 3) + ((t & 1) << 2);
    const float4 bb = *(const float4*)(b1 + nb);
    const int c = t >> 1, s = (t & 1) * 4;
#pragma unroll
    for (int eg = 0; eg < 2; ++eg) {
      mf[c][eg][s + 0] = (short)f2bf(silu_f(acc1[t][eg][0] + bb.x));
      mf[c][eg][s + 1] = (short)f2bf(silu_f(acc1[t][eg][1] + bb.y));
      mf[c][eg][s + 2] = (short)f2bf(silu_f(acc1[t][eg][2] + bb.z));
      mf[c][eg][s + 3] = (short)f2bf(silu_f(acc1[t][eg][3] + bb.w));
    }
  }
  __syncthreads();   // s2: all A reads done (m2 overlays A)

  // ---- GEMM2: acc2[t][eg] = W2_tile_t^T x m1 (B-frags from registers) ----
  f32x4 acc2[8][2];
#pragma unroll
  for (int t = 0; t < 8; ++t)
#pragma unroll
    for (int eg = 0; eg < 2; ++eg) acc2[t][eg] = (f32x4){0.f, 0.f, 0.f, 0.f};
  {
    const ushort* wp = w2cs + lrow * 32 + lq * 8;
    short8b wc[8];
#pragma unroll
    for (int t = 0; t < 8; ++t) wc[t] = *(const short8b*)(wp + t * 512);
#pragma unroll
    for (int kt = 0; kt < 4; ++kt) {
      short8b wn[8];
      if (kt < 3) {
#pragma unroll
        for (int t = 0; t < 8; ++t)
          wn[t] = *(const short8b*)(wp + (kt + 1) * 4096 + t * 512);
      }
#pragma unroll
      for (int t = 0; t < 8; ++t) {
        acc2[t][0] = __builtin_amdgcn_mfma_f32_16x16x32_bf16(wc[t], mf[kt][0], acc2[t][0], 0, 0, 0);
        acc2[t][1] = __builtin_amdgcn_mfma_f32_16x16x32_bf16(wc[t], mf[kt][1], acc2[t][1], 0, 0, 0);
      }
      if (kt < 3) {
#pragma unroll
        for (int t = 0; t < 8; ++t) wc[t] = wn[t];
      }
    }
  }

  // ---- bias + silu -> m2 (f32) vector writes over own A rows ----
  {
    float* m2w = (float*)A;
#pragma unroll
    for (int t = 0; t < 8; ++t) {
      const int nb = ((t >> 1) << 5) + (lq << 3) + ((t & 1) << 2);
      const float4 bb = *(const float4*)(b2 + nb);
#pragma unroll
      for (int eg = 0; eg < 2; ++eg) {
        f32x4 v;
        v[0] = silu_f(acc2[t][eg][0] + bb.x);
        v[1] = silu_f(acc2[t][eg][1] + bb.y);
        v[2] = silu_f(acc2[t][eg][2] + bb.z);
        v[3] = silu_f(acc2[t][eg][3] + bb.w);
        const int er = eg ? erow1 : erow0;
        *(f32x4*)(m2w + er * 148 + nb) = v;
      }
    }
  }
  __syncthreads();   // s3: m2 ready

  // ---- segmented reduce over sorted rows; plain stores, no atomics ----
  const float* m2 = (const float*)A;
  const int e2 = tid & 127, cg = tid >> 7, cb = cg * 64;
  const int r_e = rows[e2];
  const bool leader = (e2 == 0) || (rows[e2 - 1] != r_e);
  if (leader) {
    f32x4 sum[16];
#pragma unroll
    for (int q = 0; q < 16; ++q) sum[q] = *(const f32x4*)(m2 + e2 * 148 + cb + q * 4);
    int f = e2 + 1;
    while (f < EPB && rows[f] == r_e) {
#pragma unroll
      for (int q = 0; q < 16; ++q) sum[q] += *(const f32x4*)(m2 + f * 148 + cb + q * 4);
      ++f;
    }
    float* dst = (e2 == 0 && cstart[r_e] < i0)
                     ? headp + (size_t)blockIdx.x * HDIM + cb   // continuation
                     : agg + (size_t)r_e * HDIM + cb;           // sole writer
#pragma unroll
    for (int q = 0; q < 16; ++q) *(f32x4*)(dst + q * 4) = sum[q];
  }
}

// ==================== MFMA node update (folds headp) ====================
// Swapped/wave-owned structure; RMSNorm fully in-wave (2 shfl); NOTE: headp
// block indices now use >>7 because edge blocks are 128 edges wide.
__global__ __launch_bounds__(256, 2) void node_mfma_kernel(
    float* __restrict__ out_h, const float* __restrict__ agg,
    const int* __restrict__ cstart, const int* __restrict__ cend,
    const float* __restrict__ headp,
    const ushort* __restrict__ enccs, const float* __restrict__ encb,
    const ushort* __restrict__ wqdcs, const float* __restrict__ decb,
    ushort* __restrict__ hbf) {
  __shared__ ushort A[NPB * NAS];
  const int tid = threadIdx.x;
  const int n0 = blockIdx.x * NPB;

  const int lane = tid & 63, wave = tid >> 6;
  const int lrow = lane & 15, lq = lane >> 4;
  const int erow = wave * 16 + lrow;

  {
    const int e = tid >> 2, j = tid & 3;
    int node = n0 + e;
    if (node >= N_NODES) node = N_NODES - 1;
    if (j < 2) {
      const float4* s4 = (const float4*)(out_h + (size_t)node * HDIM + j * 64);
      ushort* dst = A + e * NAS + j * 64;
#pragma unroll
      for (int i = 0; i < 16; ++i) {
        float4 v = s4[i];
        ushort4 o;
        o.x = f2bf(v.x); o.y = f2bf(v.y); o.z = f2bf(v.z); o.w = f2bf(v.w);
        ((ushort4*)dst)[i] = o;
      }
    } else {
      const int s = cstart[node], en = cend[node];
      const bool hasAgg = en > s;
      const float4* a4 = (const float4*)(agg + (size_t)node * HDIM + (j - 2) * 64);
      const int bb0 = (s >> 7) + 1;
      const int bb1 = hasAgg ? ((en - 1) >> 7) : 0;
      ushort* dst = A + e * NAS + 128 + (j - 2) * 64;
#pragma unroll
      for (int i = 0; i < 16; ++i) {
        float4 v = hasAgg ? a4[i] : make_float4(0.f, 0.f, 0.f, 0.f);
        for (int bb = bb0; bb <= bb1; ++bb) {
          float4 hv = *(const float4*)(headp + (size_t)bb * HDIM + (j - 2) * 64 + i * 4);
          v.x += hv.x; v.y += hv.y; v.z += hv.z; v.w += hv.w;
        }
        ushort4 o;
        o.x = f2bf(v.x * 0.01f); o.y = f2bf(v.y * 0.01f);
        o.z = f2bf(v.z * 0.01f); o.w = f2bf(v.w * 0.01f);
        ((ushort4*)dst)[i] = o;
      }
    }
  }
  __syncthreads();

  // ---- GEMM1: q_in tiles (with 1-deep weight prefetch) ----
  f32x4 acc[8];
#pragma unroll
  for (int t = 0; t < 8; ++t) acc[t] = (f32x4){0.f, 0.f, 0.f, 0.f};
  {
    const ushort* wp = enccs + lrow * 32 + lq * 8;
    const ushort* ap = A + erow * NAS + lq * 8;
    short8b wc[8];
#pragma unroll
    for (int t = 0; t < 8; ++t) wc[t] = *(const short8b*)(wp + t * 512);
#pragma unroll
    for (int kt = 0; kt < 8; ++kt) {
      short8b wn[8];
      if (kt < 7) {
#pragma unroll
        for (int t = 0; t < 8; ++t)
          wn[t] = *(const short8b*)(wp + (kt + 1) * 4096 + t * 512);
      }
      short8b af = *(const short8b*)(ap + kt * 32);
#pragma unroll
      for (int t = 0; t < 8; ++t)
        acc[t] = __builtin_amdgcn_mfma_f32_16x16x32_bf16(wc[t], af, acc[t], 0, 0, 0);
      if (kt < 7) {
#pragma unroll
        for (int t = 0; t < 8; ++t) wc[t] = wn[t];
      }
    }
  }

  // ---- bias + in-wave sum of squares (lane has 32 of 128 dims) ----
  float q[8][4];
  float ss = 0.f;
#pragma unroll
  for (int t = 0; t < 8; ++t) {
    const int nb = ((t >> 1) << 5) + (lq << 3) + ((t & 1) << 2);
    const float4 bb = *(const float4*)(encb + nb);
    q[t][0] = acc[t][0] + bb.x;
    q[t][1] = acc[t][1] + bb.y;
    q[t][2] = acc[t][2] + bb.z;
    q[t][3] = acc[t][3] + bb.w;
    ss += q[t][0] * q[t][0] + q[t][1] * q[t][1] + q[t][2] * q[t][2] + q[t][3] * q[t][3];
  }
  ss += __shfl_xor(ss, 16, 64);
  ss += __shfl_xor(ss, 32, 64);
  const float inv = 1.0f / sqrtf(ss + 1e-12f);

  short8b mf[4];
#pragma unroll
  for (int t = 0; t < 8; ++t) {
    const int c = t >> 1, s = (t & 1) * 4;
    mf[c][s + 0] = (short)f2bf(q[t][0] * inv);
    mf[c][s + 1] = (short)f2bf(q[t][1] * inv);
    mf[c][s + 2] = (short)f2bf(q[t][2] * inv);
    mf[c][s + 3] = (short)f2bf(q[t][3] * inv);
  }

  // ---- GEMM2: wqd ----
  f32x4 acc2[8];
#pragma unroll
  for (int t = 0; t < 8; ++t) acc2[t] = (f32x4){0.f, 0.f, 0.f, 0.f};
  {
    const ushort* wp = wqdcs + lrow * 32 + lq * 8;
    short8b wc[8];
#pragma unroll
    for (int t = 0; t < 8; ++t) wc[t] = *(const short8b*)(wp + t * 512);
#pragma unroll
    for (int kt = 0; kt < 4; ++kt) {
      short8b wn[8];
      if (kt < 3) {
#pragma unroll
        for (int t = 0; t < 8; ++t)
          wn[t] = *(const short8b*)(wp + (kt + 1) * 4096 + t * 512);
      }
#pragma unroll
      for (int t = 0; t < 8; ++t)
        acc2[t] = __builtin_amdgcn_mfma_f32_16x16x32_bf16(wc[t], mf[kt], acc2[t], 0, 0, 0);
      if (kt < 3) {
#pragma unroll
        for (int t = 0; t < 8; ++t) wc[t] = wn[t];
      }
    }
  }

  // ---- h += dec(qs) + dec_b : vectorized RMW, lane owns 32 of 128 cols ----
  const int node = n0 + erow;
  if (node < N_NODES) {
#pragma unroll
    for (int t = 0; t < 8; ++t) {
      const int nb = ((t >> 1) << 5) + (lq << 3) + ((t & 1) << 2);
      const float4 db = *(const float4*)(decb + nb);
      const size_t off = (size_t)node * HDIM + nb;
      float4 o = *(const float4*)(out_h + off);
      float4 hn;
      hn.x = o.x + acc2[t][0] + db.x;
      hn.y = o.y + acc2[t][1] + db.y;
      hn.z = o.z + acc2[t][2] + db.z;
      hn.w = o.w + acc2[t][3] + db.w;
      *(float4*)(out_h + off) = hn;
      ushort4 ob;
      ob.x = f2bf(hn.x); ob.y = f2bf(hn.y); ob.z = f2bf(hn.z); ob.w = f2bf(hn.w);
      *(ushort4*)(hbf + off) = ob;
    }
  }
}

// ==================== MFMA coordinate head =================================
// Same EPB=128 / 2-edge-group / prefetched structure as edge_mfma.
__global__ __launch_bounds__(256, 2) void coord_mfma_kernel(
    const ushort* __restrict__ hbf, const int* __restrict__ ei,
    const float* __restrict__ x, const float* __restrict__ ea,
    const int* __restrict__ elist,
    const ushort* __restrict__ w1cs, const float* __restrict__ b1,
    const ushort* __restrict__ w2cs, const float* __restrict__ b2,
    const float* __restrict__ w3, float* __restrict__ xout) {
  __shared__ ushort A[EPB * AS];
  __shared__ int rows[EPB];
  __shared__ int colsA[EPB];
  __shared__ float tv[EPB];

  const int tid = threadIdx.x;
  const int lane = tid & 63, wave = tid >> 6;
  const int lrow = lane & 15, lq = lane >> 4;
  const int erow0 = wave * 32 + lrow;
  const int erow1 = erow0 + 16;

  const int i0 = blockIdx.x * EPB;
#pragma unroll
  for (int it = 0; it < 2; ++it) {
    const int e = it * 64 + (tid >> 2), j = tid & 3;
    const int edge = elist[i0 + e];
    const int r = ei[edge], c = ei[N_EDGES + edge];
    if (j == 0) { rows[e] = r; colsA[e] = c; }
    const uint4* hr = (const uint4*)(hbf + (size_t)r * HDIM + j * 32);
    const uint4* hc = (const uint4*)(hbf + (size_t)c * HDIM + j * 32);
    uint4* d1 = (uint4*)(A + e * AS + j * 32);
    uint4* d2 = (uint4*)(A + e * AS + 128 + j * 32);
    d1[0] = hr[0]; d1[1] = hr[1]; d1[2] = hr[2]; d1[3] = hr[3];
    d2[0] = hc[0]; d2[1] = hc[1]; d2[2] = hc[2]; d2[3] = hc[3];
    if (j == 3) {
      float dx = x[r * 3 + 0] - x[c * 3 + 0];
      float dy = x[r * 3 + 1] - x[c * 3 + 1];
      float dz = x[r * 3 + 2] - x[c * 3 + 2];
      ushort* dst = A + e * AS;
      dst[256] = f2bf(dx * dx + dy * dy + dz * dz);
      dst[257] = f2bf(ea[edge]);
#pragma unroll
      for (int z = 258; z < 288; ++z) dst[z] = 0;
    }
  }
  __syncthreads();   // s1: A ready

  f32x4 acc1[8][2];
#pragma unroll
  for (int t = 0; t < 8; ++t)
#pragma unroll
    for (int eg = 0; eg < 2; ++eg) acc1[t][eg] = (f32x4){0.f, 0.f, 0.f, 0.f};
  {
    const ushort* wp = w1cs + lrow * 32 + lq * 8;
    const ushort* ap0 = A + erow0 * AS + lq * 8;
    const ushort* ap1 = A + erow1 * AS + lq * 8;
    short8b wc[8];
#pragma unroll
    for (int t = 0; t < 8; ++t) wc[t] = *(const short8b*)(wp + t * 512);
#pragma unroll
    for (int kt = 0; kt < 9; ++kt) {
      short8b wn[8];
      if (kt < 8) {
#pragma unroll
        for (int t = 0; t < 8; ++t)
          wn[t] = *(const short8b*)(wp + (kt + 1) * 4096 + t * 512);
      }
      short8b af0 = *(const short8b*)(ap0 + kt * 32);
      short8b af1 = *(const short8b*)(ap1 + kt * 32);
#pragma unroll
      for (int t = 0; t < 8; ++t) {
        acc1[t][0] = __builtin_amdgcn_mfma_f32_16x16x32_bf16(wc[t], af0, acc1[t][0], 0, 0, 0);
        acc1[t][1] = __builtin_amdgcn_mfma_f32_16x16x32_bf16(wc[t], af1, acc1[t][1], 0, 0, 0);
      }
      if (kt < 8) {
#pragma unroll
        for (int t = 0; t < 8; ++t) wc[t] = wn[t];
      }
    }
  }

  short8b mf[4][2];
#pragma unroll
  for (int t = 0; t < 8; ++t) {
    const int nb = ((t >> 1) << 5) + (lq << 3) + ((t & 1) << 2);
    const float4 bb = *(const float4*)(b1 + nb);
    const int c = t >> 1, s = (t & 1) * 4;
#pragma unroll
    for (int eg = 0; eg < 2; ++eg) {
      mf[c][eg][s + 0] = (short)f2bf(silu_f(acc1[t][eg][0] + bb.x));
      mf[c][eg][s + 1] = (short)f2bf(silu_f(acc1[t][eg][1] + bb.y));
      mf[c][eg][s + 2] = (short)f2bf(silu_f(acc1[t][eg][2] + bb.z));
      mf[c][eg][s + 3] = (short)f2bf(silu_f(acc1[t][eg][3] + bb.w));
    }
  }

  f32x4 acc2[8][2];
#pragma unroll
  for (int t = 0; t < 8; ++t)
#pragma unroll
    for (int eg = 0; eg < 2; ++eg) acc2[t][eg] = (f32x4){0.f, 0.f, 0.f, 0.f};
  {
    const ushort* wp = w2cs + lrow * 32 + lq * 8;
    short8b wc[8];
#pragma unroll
    for (int t = 0; t < 8; ++t) wc[t] = *(const short8b*)(wp + t * 512);
#pragma unroll
    for (int kt = 0; kt < 4; ++kt) {
      short8b wn[8];
      if (kt < 3) {
#pragma unroll
        for (int t = 0; t < 8; ++t)
          wn[t] = *(const short8b*)(wp + (kt + 1) * 4096 + t * 512);
      }
#pragma unroll
      for (int t = 0; t < 8; ++t) {
        acc2[t][0] = __builtin_amdgcn_mfma_f32_16x16x32_bf16(wc[t], mf[kt][0], acc2[t][0], 0, 0, 0);
        acc2[t][1] = __builtin_amdgcn_mfma_f32_16x16x32_bf16(wc[t], mf[kt][1], acc2[t][1], 0, 0, 0);
      }
      if (kt < 3) {
#pragma unroll
        for (int t = 0; t < 8; ++t) wc[t] = wn[t];
      }
    }
  }

  // ---- t-scalar: per-lane partial over its 32 cols, reduce across lq ----
  float tp0 = 0.f, tp1 = 0.f;
#pragma unroll
  for (int t = 0; t < 8; ++t) {
    const int nb = ((t >> 1) << 5) + (lq << 3) + ((t & 1) << 2);
    const float4 bb = *(const float4*)(b2 + nb);
    const float4 wf = *(const float4*)(w3 + nb);
    tp0 += silu_f(acc2[t][0][0] + bb.x) * wf.x;
    tp0 += silu_f(acc2[t][0][1] + bb.y) * wf.y;
    tp0 += silu_f(acc2[t][0][2] + bb.z) * wf.z;
    tp0 += silu_f(acc2[t][0][3] + bb.w) * wf.w;
    tp1 += silu_f(acc2[t][1][0] + bb.x) * wf.x;
    tp1 += silu_f(acc2[t][1][1] + bb.y) * wf.y;
    tp1 += silu_f(acc2[t][1][2] + bb.z) * wf.z;
    tp1 += silu_f(acc2[t][1][3] + bb.w) * wf.w;
  }
  tp0 += __shfl_xor(tp0, 16, 64);
  tp0 += __shfl_xor(tp0, 32, 64);
  tp1 += __shfl_xor(tp1, 16, 64);
  tp1 += __shfl_xor(tp1, 32, 64);
  if (lq == 0) { tv[erow0] = tp0 * 0.01f; tv[erow1] = tp1 * 0.01f; }
  __syncthreads();   // s2: tv ready

  if (tid < EPB) {
    const int e = tid;
    const int r_e = rows[e];
    const bool leader = (e == 0) || (rows[e - 1] != r_e);
    if (leader) {
      float sx = 0.f, sy = 0.f, sz = 0.f;
      int f = e;
      do {
        const int c = colsA[f];
        float dx = x[r_e * 3 + 0] - x[c * 3 + 0];
        float dy = x[r_e * 3 + 1] - x[c * 3 + 1];
        float dz = x[r_e * 3 + 2] - x[c * 3 + 2];
        float radial = dx * dx + dy * dy + dz * dz;
        float s = 1.0f / (sqrtf(radial + 1e-8f) + 1.0f);
        float t = tv[f];
        sx += dx * s * t; sy += dy * s * t; sz += dz * s * t;
        ++f;
      } while (f < EPB && rows[f] == r_e);
      atomicAdd(&xout[r_e * 3 + 0], sx);
      atomicAdd(&xout[r_e * 3 + 1], sy);
      atomicAdd(&xout[r_e * 3 + 2], sz);
    }
  }
}

extern "C" void kernel_launch(void* const* d_in, const int* in_sizes, int n_in,
                              void* d_out, int out_size, void* d_ws, size_t ws_size,
                              hipStream_t stream) {
  const float* h     = (const float*)d_in[0];
  const float* x     = (const float*)d_in[1];
  const int*   ei    = (const int*)d_in[2];
  const float* ea    = (const float*)d_in[3];
  const float* e_w1  = (const float*)d_in[4];
  const float* e_b1  = (const float*)d_in[5];
  const float* e_w2  = (const float*)d_in[6];
  const float* e_b2  = (const float*)d_in[7];
  const float* enc_w = (const float*)d_in[8];
  const float* enc_b = (const float*)d_in[9];
  const float* coeffs= (const float*)d_in[10];
  const float* A_re  = (const float*)d_in[11];
  const float* A_im  = (const float*)d_in[12];
  const float* dec_w = (const float*)d_in[13];
  const float* dec_b = (const float*)d_in[14];
  const float* c_w1  = (const float*)d_in[15];
  const float* c_b1  = (const float*)d_in[16];
  const float* c_w2  = (const float*)d_in[17];
  const float* c_b2  = (const float*)d_in[18];
  const float* c_w3  = (const float*)d_in[19];

  float* out = (float*)d_out;
  float* ws  = (float*)d_ws;

  // workspace layout (float offsets) — ~33.1 MB
  float*  agg    = ws;                          // 3,840,000
  float2* xa     = (float2*)(ws + 3840000);     // 131,072 f
  float2* xb     = (float2*)(ws + 3971072);     // 131,072 f
  float2* xt     = (float2*)(ws + 4102144);     // 131,072 f
  float2* qm     = (float2*)(ws + 4233216);     // 131,072 f
  float2* gkm    = (float2*)(ws + 4364288);     // 131,072 f
  float2* njm    = (float2*)(ws + 4495360);     // 131,072 f
  float2* um     = (float2*)(ws + 4626432);     //  65,536 f
  float*  wqd    = ws + 4691968;                //  32,768 f
  int*    perm   = (int*)(ws + 4724736);        //     128
  int*    cursor = (int*)(ws + 4724864);        //  30,000 (post-fill: CSR ends)
  int*    cstart = (int*)(ws + 4754864);        //  30,000 (CSR starts)
  int*    elist  = (int*)(ws + 4784864);        // 480,000
  float*  headp  = ws + 5264864;                // 3750*128 used (960,000 reserved)
  ushort* hbf    = (ushort*)(ws + 6224864);     // 1,920,000 f
  ushort* w1cs   = (ushort*)(ws + 8144864);
  ushort* w2cs   = (ushort*)(ws + 8181728);
  ushort* cw1cs  = (ushort*)(ws + 8198112);
  ushort* cw2cs  = (ushort*)(ws + 8216544);
  ushort* enccs  = (ushort*)(ws + 8224736);
  ushort* wqdcs  = (ushort*)(ws + 8257504);

  init_out_kernel<<<15000, 256, 0, stream>>>(h, x, out);

  // counting sort of edges by destination row (cstart kept immutable)
  hipMemsetAsync(cursor, 0, N_NODES * sizeof(int), stream);
  count_kernel<<<1875, 256, 0, stream>>>(ei, cursor);
  scan_kernel<<<1, 1024, 0, stream>>>(cursor, cstart);
  fill_kernel<<<1875, 256, 0, stream>>>(ei, cursor, elist);

  // quantum-operator precompute: Newton-Schulz inverse + tiny GEMM chain
  perm_kernel<<<1, 128, 0, stream>>>(perm);
  ns_init_kernel<<<dim3(64, 4), 256, 0, stream>>>(A_re, A_im, xa);
  float2* cur = xa;
  float2* nxt = xb;
  for (int it = 0; it < 4; ++it) {
    ns_bx_kernel<<<dim3(64, 4), 256, 0, stream>>>(A_re, A_im, cur, xt);
    ns_upd_kernel<<<dim3(64, 4), 256, 0, stream>>>(cur, xt, nxt);
    float2* tmp = cur; cur = nxt; nxt = tmp;
  }
  qmat_kernel<<<dim3(64, 4), 256, 0, stream>>>(A_re, A_im, cur, qm);
  gk_kernel<<<dim3(64, 4), 256, 0, stream>>>(coeffs, gkm);
  nj_kernel<<<dim3(64, 4), 256, 0, stream>>>(qm, gkm, perm, njm);
  compose_kernel<<<dim3(64, 2), 256, 0, stream>>>(njm, um);
  wqd_kernel<<<dim3(64, 2), 256, 0, stream>>>(um, dec_w, wqd);

  // weight conversions to chunked bf16 [kt][p][kk] with permuted columns
  for (int l = 0; l < 2; ++l) {
    convert_w_kernel<<<144, 256, 0, stream>>>(e_w1 + (size_t)l * 258 * HDIM,
                                              w1cs + (size_t)l * 9 * 4096, 258, 9);
    convert_w_kernel<<<64, 256, 0, stream>>>(e_w2 + (size_t)l * HDIM * HDIM,
                                             w2cs + (size_t)l * 4 * 4096, 128, 4);
    convert_w_kernel<<<128, 256, 0, stream>>>(enc_w + (size_t)l * 256 * HDIM,
                                              enccs + (size_t)l * 8 * 4096, 256, 8);
    convert_w_kernel<<<64, 256, 0, stream>>>(wqd + (size_t)l * HDIM * HDIM,
                                             wqdcs + (size_t)l * 4 * 4096, 128, 4);
  }
  convert_w_kernel<<<144, 256, 0, stream>>>(c_w1, cw1cs, 258, 9);
  convert_w_kernel<<<64, 256, 0, stream>>>(c_w2, cw2cs, 128, 4);

  // initial bf16 h
  h_to_bf_kernel<<<3750, 256, 0, stream>>>(out, hbf);

  // two message-passing layers
  for (int l = 0; l < 2; ++l) {
    edge_mfma_kernel<<<N_EDGES / EPB, 256, 0, stream>>>(
        hbf, ei, x, ea, elist, cstart,
        w1cs + (size_t)l * 9 * 4096, e_b1 + l * HDIM,
        w2cs + (size_t)l * 4 * 4096, e_b2 + l * HDIM, agg, headp);
    node_mfma_kernel<<<(N_NODES + NPB - 1) / NPB, 256, 0, stream>>>(
        out, agg, cstart, cursor, headp,
        enccs + (size_t)l * 8 * 4096, enc_b + l * HDIM,
        wqdcs + (size_t)l * 4 * 4096, dec_b + l * HDIM, hbf);
  }

  // coordinate head
  coord_mfma_kernel<<<N_EDGES / EPB, 256, 0, stream>>>(
      hbf, ei, x, ea, elist, cw1cs, c_b1, cw2cs, c_b2, c_w3,
      out + (size_t)N_NODES * HDIM);
}

// Round 3
// 770.119 us; speedup vs baseline: 1.4468x; 1.3502x over previous
//
#include <hip/hip_runtime.h>
#include <math.h>

#define N_NODES 30000
#define N_EDGES 480000
#define HDIM 128
#define EPB 64        // edges (or nodes) per MFMA block; max node degree (~40)
                      // must be < EPB so a node's CSR range spans <=2 blocks.
#define AS 296        // A-tile row stride (bf16)
#define NAS 264       // node A-tile row stride (bf16)
#define MS 136        // m1 row stride (bf16) / m2 stride (f32)

typedef __attribute__((ext_vector_type(8))) short short8b;
typedef __attribute__((ext_vector_type(4))) float f32x4;

__device__ __forceinline__ float silu_f(float v) {
  return v / (1.0f + __expf(-v));
}

__device__ __forceinline__ unsigned short f2bf(float f) {
  unsigned int u = __float_as_uint(f);
  unsigned int r = u + 0x7fffu + ((u >> 16) & 1u);
  return (unsigned short)(r >> 16);
}

// ------------- fused output init + bf16 cast: out = [h | x], hbf = bf16(h) --
__global__ void init_out_bf_kernel(const float* __restrict__ h,
                                   const float* __restrict__ x,
                                   float* __restrict__ out,
                                   ushort* __restrict__ hbf) {
  int idx = blockIdx.x * 256 + threadIdx.x;   // 960,000 float4 units
  float4 v = ((const float4*)h)[idx];
  ((float4*)out)[idx] = v;
  ushort4 o;
  o.x = f2bf(v.x); o.y = f2bf(v.y); o.z = f2bf(v.z); o.w = f2bf(v.w);
  ((ushort4*)hbf)[idx] = o;
  if (idx < N_NODES * 3 / 4) {
    ((float4*)(out + N_NODES * HDIM))[idx] = ((const float4*)x)[idx];
  }
}

// -------- fused weight convert: all static weights in ONE launch ----------
// chunk layout per matrix: [KT][128][32] bf16, dst[kt*4096 + n*32 + kk],
// k = kt*32+kk (zero-padded past Kreal).
// chunk index map (55 chunks x 4096):
//   0-17  e_w1 (l0:0-8, l1:9-17)     K=258
//   18-25 e_w2 (l0:18-21, l1:22-25)  K=128
//   26-41 enc_w (l0:26-33, l1:34-41) K=256
//   42-50 c_w1                       K=258
//   51-54 c_w2                       K=128
__global__ void convert_all_kernel(
    const float* __restrict__ e_w1, const float* __restrict__ e_w2,
    const float* __restrict__ enc_w, const float* __restrict__ c_w1,
    const float* __restrict__ c_w2,
    ushort* __restrict__ w1cs, ushort* __restrict__ w2cs,
    ushort* __restrict__ enccs, ushort* __restrict__ cw1cs,
    ushort* __restrict__ cw2cs) {
  int idx = blockIdx.x * 256 + threadIdx.x;
  if (idx >= 55 * 4096) return;
  int ci = idx >> 12, rem = idx & 4095, n = rem >> 5, kk = rem & 31;
  const float* W;
  ushort* dst;
  int Kreal, ktl;
  if (ci < 18) {
    int l = ci / 9; ktl = ci - l * 9;
    W = e_w1 + (size_t)l * 258 * HDIM; dst = w1cs + (size_t)l * 9 * 4096;
    Kreal = 258;
  } else if (ci < 26) {
    int c2 = ci - 18; int l = c2 >> 2; ktl = c2 & 3;
    W = e_w2 + (size_t)l * HDIM * HDIM; dst = w2cs + (size_t)l * 4 * 4096;
    Kreal = 128;
  } else if (ci < 42) {
    int c2 = ci - 26; int l = c2 >> 3; ktl = c2 & 7;
    W = enc_w + (size_t)l * 256 * HDIM; dst = enccs + (size_t)l * 8 * 4096;
    Kreal = 256;
  } else if (ci < 51) {
    ktl = ci - 42; W = c_w1; dst = cw1cs; Kreal = 258;
  } else {
    ktl = ci - 51; W = c_w2; dst = cw2cs; Kreal = 128;
  }
  int k = ktl * 32 + kk;
  float v = (k < Kreal) ? W[(size_t)k * HDIM + n] : 0.0f;
  dst[ktl * 4096 + rem] = f2bf(v);
}

// ---------------- counting sort of edges by destination row ----------------
__global__ void count_kernel(const int* __restrict__ ei, int* __restrict__ cursor) {
  int e = blockIdx.x * 256 + threadIdx.x;
  atomicAdd(&cursor[ei[e]], 1);
}

__global__ __launch_bounds__(1024) void scan_kernel(int* __restrict__ cursor,
                                                    int* __restrict__ cstart) {
  __shared__ int sums[1024];
  const int tid = threadIdx.x;
  const int base = tid * 30;
  int local[30];
  int s = 0;
#pragma unroll
  for (int j = 0; j < 30; ++j) {
    int idx = base + j;
    int d = (idx < N_NODES) ? cursor[idx] : 0;
    local[j] = s;
    s += d;
  }
  sums[tid] = s;
  __syncthreads();
  for (int off = 1; off < 1024; off <<= 1) {
    int add = (tid >= off) ? sums[tid - off] : 0;
    __syncthreads();
    sums[tid] += add;
    __syncthreads();
  }
  int excl = (tid == 0) ? 0 : sums[tid - 1];
#pragma unroll
  for (int j = 0; j < 30; ++j) {
    int idx = base + j;
    if (idx < N_NODES) {
      int v = excl + local[j];
      cursor[idx] = v;
      cstart[idx] = v;   // immutable CSR starts (cursor mutates in fill)
    }
  }
}

__global__ void fill_kernel(const int* __restrict__ ei, int* __restrict__ cursor,
                            int* __restrict__ elist) {
  int e = blockIdx.x * 256 + threadIdx.x;
  int r = ei[e];
  int pos = atomicAdd(&cursor[r], 1);   // after this kernel cursor[n] = CSR end
  elist[pos] = e;
}

// ============ Newton-Schulz inverse of B = A_h + iI ============
// ||A_h|| ~ 0.32 => E0 = -A_h^2, ||E0|| ~ 0.1; 3 quadratic iterations ->
// 0.1^8 = 1e-8 residual (way below bf16 pipeline precision).
__global__ void ns_init_kernel(const float* __restrict__ Are,
                               const float* __restrict__ Aim,
                               float2* __restrict__ X) {
  int lj = blockIdx.y;
  int idx = blockIdx.x * 256 + threadIdx.x;
  int r = idx >> 7, c = idx & 127;
  const float* are = Are + (size_t)lj * 16384;
  const float* aim = Aim + (size_t)lj * 16384;
  float re = are[r * 128 + c] + are[c * 128 + r];
  float im = aim[r * 128 + c] - aim[c * 128 + r];
  if (r == c) im -= 1.0f;
  X[(size_t)lj * 16384 + idx] = make_float2(re, im);
}

__global__ void ns_bx_kernel(const float* __restrict__ Are,
                             const float* __restrict__ Aim,
                             const float2* __restrict__ X,
                             float2* __restrict__ T) {
  int lj = blockIdx.y;
  int idx = blockIdx.x * 256 + threadIdx.x;
  int r = idx >> 7, c = idx & 127;
  const float* are = Are + (size_t)lj * 16384;
  const float* aim = Aim + (size_t)lj * 16384;
  const float2* x = X + (size_t)lj * 16384;
  float2 acc = make_float2(0.f, 0.f);
  for (int k = 0; k < 128; ++k) {
    float re = are[r * 128 + k] + are[k * 128 + r];
    float im = aim[r * 128 + k] - aim[k * 128 + r];
    if (k == r) im += 1.0f;
    float2 b = x[k * 128 + c];
    acc.x += re * b.x - im * b.y;
    acc.y += re * b.y + im * b.x;
  }
  T[(size_t)lj * 16384 + idx] = acc;
}

__global__ void ns_upd_kernel(const float2* __restrict__ X,
                              const float2* __restrict__ T,
                              float2* __restrict__ Xn) {
  int lj = blockIdx.y;
  int idx = blockIdx.x * 256 + threadIdx.x;
  int r = idx >> 7, c = idx & 127;
  const float2* x = X + (size_t)lj * 16384;
  const float2* t = T + (size_t)lj * 16384;
  float2 acc = make_float2(0.f, 0.f);
  for (int k = 0; k < 128; ++k) {
    float2 a = x[r * 128 + k];
    float2 b = t[k * 128 + c];
    acc.x += a.x * b.x - a.y * b.y;
    acc.y += a.x * b.y + a.y * b.x;
  }
  float2 xc = x[r * 128 + c];
  Xn[(size_t)lj * 16384 + idx] = make_float2(2.f * xc.x - acc.x, 2.f * xc.y - acc.y);
}

// ---------------- q = (A_h - iI) * Binv ----------------
__global__ void qmat_kernel(const float* __restrict__ Are,
                            const float* __restrict__ Aim,
                            const float2* __restrict__ binvg,
                            float2* __restrict__ qm) {
  int lj = blockIdx.y;
  int idx = blockIdx.x * 256 + threadIdx.x;
  int r = idx >> 7, c = idx & 127;
  const float* are = Are + (size_t)lj * 16384;
  const float* aim = Aim + (size_t)lj * 16384;
  const float2* binv = binvg + (size_t)lj * 16384;
  float2 acc = make_float2(0.f, 0.f);
  for (int k = 0; k < 128; ++k) {
    float re = are[r * 128 + k] + are[k * 128 + r];
    float im = aim[r * 128 + k] - aim[k * 128 + r];
    if (k == r) im -= 1.0f;
    float2 b = binv[k * 128 + c];
    acc.x += re * b.x - im * b.y;
    acc.y += re * b.y + im * b.x;
  }
  qm[(size_t)lj * 16384 + idx] = acc;
}

// ---------------- Gk = (RY*RX)^(kron 7) ----------------
__global__ void gk_kernel(const float* __restrict__ coeffs,
                          float2* __restrict__ gkm) {
  int lj = blockIdx.y;
  float a = coeffs[lj * 2 + 0], b = coeffs[lj * 2 + 1];
  float ca = cosf(0.5f * a), sa = sinf(0.5f * a);
  float cb = cosf(0.5f * b), sb = sinf(0.5f * b);
  float2 G[2][2];
  G[0][0] = make_float2(cb * ca, sb * sa);
  G[0][1] = make_float2(-sb * ca, -cb * sa);
  G[1][0] = make_float2(sb * ca, -cb * sa);
  G[1][1] = make_float2(cb * ca, -sb * sa);
  int idx = blockIdx.x * 256 + threadIdx.x;
  int r = idx >> 7, c = idx & 127;
  float2 acc = make_float2(1.f, 0.f);
#pragma unroll
  for (int bit = 6; bit >= 0; --bit) {
    float2 g = G[(r >> bit) & 1][(c >> bit) & 1];
    acc = make_float2(acc.x * g.x - acc.y * g.y, acc.x * g.y + acc.y * g.x);
  }
  gkm[(size_t)lj * 16384 + idx] = acc;
}

// ------- N_j[i][c] = sum_k q[k][i] * Gk[g[c]][k]  (CNOT perm inlined) ------
__global__ void nj_kernel(const float2* __restrict__ qm,
                          const float2* __restrict__ gkm,
                          float2* __restrict__ njm) {
  int lj = blockIdx.y;
  int idx = blockIdx.x * 256 + threadIdx.x;
  int i = idx >> 7, c = idx & 127;
  int gc;
  {
    int v = c;
    const int cs[7] = {6, 5, 4, 3, 2, 1, 0};
    const int ts[7] = {0, 6, 5, 4, 3, 2, 1};
#pragma unroll
    for (int p = 0; p < 7; ++p) {
      int cb = (v >> (6 - cs[p])) & 1;
      v = v ^ (cb << (6 - ts[p]));
    }
    gc = v;
  }
  const float2* q = qm + (size_t)lj * 16384;
  const float2* gk = gkm + (size_t)lj * 16384;
  float2 acc = make_float2(0.f, 0.f);
  for (int k = 0; k < 128; ++k) {
    float2 qa = q[k * 128 + i];
    float2 gb = gk[gc * 128 + k];
    acc.x += qa.x * gb.x - qa.y * gb.y;
    acc.y += qa.x * gb.y + qa.y * gb.x;
  }
  njm[(size_t)lj * 16384 + idx] = acc;
}

// ---------------- U_l = N_{l,0} @ N_{l,1} ----------------
__global__ void compose_kernel(const float2* __restrict__ njm,
                               float2* __restrict__ um) {
  int l = blockIdx.y;
  int idx = blockIdx.x * 256 + threadIdx.x;
  int i = idx >> 7, c = idx & 127;
  const float2* n0 = njm + (size_t)(l * 2 + 0) * 16384;
  const float2* n1 = njm + (size_t)(l * 2 + 1) * 16384;
  float2 acc = make_float2(0.f, 0.f);
  for (int k = 0; k < 128; ++k) {
    float2 a = n0[i * 128 + k];
    float2 b = n1[k * 128 + c];
    acc.x += a.x * b.x - a.y * b.y;
    acc.y += a.x * b.y + a.y * b.x;
  }
  um[(size_t)l * 16384 + idx] = acc;
}

// -------- Wqd_l = Re(U_l) @ dec_w_l, written DIRECTLY as bf16 chunks -------
__global__ void wqd_kernel(const float2* __restrict__ um,
                           const float* __restrict__ decw,
                           ushort* __restrict__ wqdcs) {
  int l = blockIdx.y;
  int idx = blockIdx.x * 256 + threadIdx.x;
  int i = idx >> 7, c = idx & 127;     // i = k-dim (D), c = n-dim (H)
  const float2* u = um + (size_t)l * 16384;
  const float* dw = decw + (size_t)l * 16384;
  float acc = 0.f;
  for (int k = 0; k < 128; ++k) acc += u[i * 128 + k].x * dw[k * 128 + c];
  wqdcs[(size_t)l * 4 * 4096 + (i >> 5) * 4096 + c * 32 + (i & 31)] = f2bf(acc);
}

// ==================== MFMA edge MLP: streamed weights, atomic-free =========
__global__ __launch_bounds__(256, 4) void edge_mfma_kernel(
    const ushort* __restrict__ hbf, const int* __restrict__ ei,
    const float* __restrict__ x, const float* __restrict__ ea,
    const int* __restrict__ elist, const int* __restrict__ cstart,
    const ushort* __restrict__ w1cs, const float* __restrict__ b1,
    const ushort* __restrict__ w2cs, const float* __restrict__ b2,
    float* __restrict__ agg, float* __restrict__ headp) {
  __shared__ ushort A[EPB * AS];      // m1 (bf16) and m2 (f32) overlay
  __shared__ int rows[EPB];
  ushort* m1 = A;
  float* m2 = (float*)A;

  const int tid = threadIdx.x;
  const int lane = tid & 63, wave = tid >> 6;
  const int lrow = lane & 15, lq = lane >> 4;
  const int wbase = wave * 32;
  const int woff0 = (wbase + lrow) * 32 + lq * 8;        // nt=0 fragment offset
  const int woff1 = (wbase + 16 + lrow) * 32 + lq * 8;   // nt=1

  const float b1v[2] = {b1[wbase + lrow], b1[wbase + 16 + lrow]};
  const float b2v[2] = {b2[wbase + lrow], b2[wbase + 16 + lrow]};

  const int i0 = blockIdx.x * EPB;
  {
    const int e = tid >> 2, j = tid & 3;
    const int edge = elist[i0 + e];
    const int r = ei[edge], c = ei[N_EDGES + edge];
    if (j == 0) rows[e] = r;
    const uint4* hr = (const uint4*)(hbf + (size_t)r * HDIM + j * 32);
    const uint4* hc = (const uint4*)(hbf + (size_t)c * HDIM + j * 32);
    uint4* d1 = (uint4*)(A + e * AS + j * 32);
    uint4* d2 = (uint4*)(A + e * AS + 128 + j * 32);
    d1[0] = hr[0]; d1[1] = hr[1]; d1[2] = hr[2]; d1[3] = hr[3];
    d2[0] = hc[0]; d2[1] = hc[1]; d2[2] = hc[2]; d2[3] = hc[3];
    if (j == 3) {
      float dx = x[r * 3 + 0] - x[c * 3 + 0];
      float dy = x[r * 3 + 1] - x[c * 3 + 1];
      float dz = x[r * 3 + 2] - x[c * 3 + 2];
      ushort* dst = A + e * AS;
      dst[256] = f2bf(dx * dx + dy * dy + dz * dz);
      dst[257] = f2bf(ea[edge]);
#pragma unroll
      for (int z = 258; z < 288; ++z) dst[z] = 0;
    }
  }
  __syncthreads();   // s1: A ready

  f32x4 acc[4][2];
#pragma unroll
  for (int mt = 0; mt < 4; ++mt)
#pragma unroll
    for (int nt = 0; nt < 2; ++nt) acc[mt][nt] = (f32x4){0.f, 0.f, 0.f, 0.f};
  {
    short8b wcur0 = *(const short8b*)(w1cs + woff0);
    short8b wcur1 = *(const short8b*)(w1cs + woff1);
#pragma unroll
    for (int kt = 0; kt < 9; ++kt) {
      short8b wn0, wn1;
      if (kt < 8) {
        wn0 = *(const short8b*)(w1cs + (kt + 1) * 4096 + woff0);
        wn1 = *(const short8b*)(w1cs + (kt + 1) * 4096 + woff1);
      }
      short8b af[4];
#pragma unroll
      for (int mt = 0; mt < 4; ++mt)
        af[mt] = *(const short8b*)(A + (mt * 16 + lrow) * AS + kt * 32 + lq * 8);
#pragma unroll
      for (int mt = 0; mt < 4; ++mt) {
        acc[mt][0] = __builtin_amdgcn_mfma_f32_16x16x32_bf16(af[mt], wcur0, acc[mt][0], 0, 0, 0);
        acc[mt][1] = __builtin_amdgcn_mfma_f32_16x16x32_bf16(af[mt], wcur1, acc[mt][1], 0, 0, 0);
      }
      if (kt < 8) { wcur0 = wn0; wcur1 = wn1; }
    }
  }
  __syncthreads();   // s2: all A reads done (m1 overlays A)
#pragma unroll
  for (int mt = 0; mt < 4; ++mt)
#pragma unroll
    for (int nt = 0; nt < 2; ++nt)
#pragma unroll
      for (int r = 0; r < 4; ++r)
        m1[(mt * 16 + lq * 4 + r) * MS + wbase + nt * 16 + lrow] =
            f2bf(silu_f(acc[mt][nt][r] + b1v[nt]));
  __syncthreads();   // s3: m1 ready

  f32x4 acc2[4][2];
#pragma unroll
  for (int mt = 0; mt < 4; ++mt)
#pragma unroll
    for (int nt = 0; nt < 2; ++nt) acc2[mt][nt] = (f32x4){0.f, 0.f, 0.f, 0.f};
  {
    short8b wcur0 = *(const short8b*)(w2cs + woff0);
    short8b wcur1 = *(const short8b*)(w2cs + woff1);
#pragma unroll
    for (int kt = 0; kt < 4; ++kt) {
      short8b wn0, wn1;
      if (kt < 3) {
        wn0 = *(const short8b*)(w2cs + (kt + 1) * 4096 + woff0);
        wn1 = *(const short8b*)(w2cs + (kt + 1) * 4096 + woff1);
      }
      short8b af[4];
#pragma unroll
      for (int mt = 0; mt < 4; ++mt)
        af[mt] = *(const short8b*)(m1 + (mt * 16 + lrow) * MS + kt * 32 + lq * 8);
#pragma unroll
      for (int mt = 0; mt < 4; ++mt) {
        acc2[mt][0] = __builtin_amdgcn_mfma_f32_16x16x32_bf16(af[mt], wcur0, acc2[mt][0], 0, 0, 0);
        acc2[mt][1] = __builtin_amdgcn_mfma_f32_16x16x32_bf16(af[mt], wcur1, acc2[mt][1], 0, 0, 0);
      }
      if (kt < 3) { wcur0 = wn0; wcur1 = wn1; }
    }
  }
  __syncthreads();   // s4: all m1 reads done (m2 overlays m1/A)
#pragma unroll
  for (int mt = 0; mt < 4; ++mt)
#pragma unroll
    for (int nt = 0; nt < 2; ++nt)
#pragma unroll
      for (int r = 0; r < 4; ++r)
        m2[(mt * 16 + lq * 4 + r) * MS + wbase + nt * 16 + lrow] =
            silu_f(acc2[mt][nt][r] + b2v[nt]);
  __syncthreads();   // s5: m2 ready

  // ---- segmented reduce over sorted rows; plain stores, no atomics ----
  const int e2 = tid & 63, cg = tid >> 6, cb = cg * 32;
  const int r_e = rows[e2];
  const bool leader = (e2 == 0) || (rows[e2 - 1] != r_e);
  if (leader) {
    f32x4 sum[8];
#pragma unroll
    for (int q = 0; q < 8; ++q) sum[q] = *(const f32x4*)(m2 + e2 * MS + cb + q * 4);
    int f = e2 + 1;
    while (f < EPB && rows[f] == r_e) {
#pragma unroll
      for (int q = 0; q < 8; ++q) sum[q] += *(const f32x4*)(m2 + f * MS + cb + q * 4);
      ++f;
    }
    float* dst = (e2 == 0 && cstart[r_e] < i0)
                     ? headp + (size_t)blockIdx.x * HDIM + cb   // continuation
                     : agg + (size_t)r_e * HDIM + cb;           // sole writer
#pragma unroll
    for (int q = 0; q < 8; ++q) *(f32x4*)(dst + q * 4) = sum[q];
  }
}

// ==================== MFMA node update (folds headp) ====================
__global__ __launch_bounds__(256, 2) void node_mfma_kernel(
    float* __restrict__ out_h, const float* __restrict__ agg,
    const int* __restrict__ cstart, const int* __restrict__ cend,
    const float* __restrict__ headp,
    const ushort* __restrict__ enccs, const float* __restrict__ encb,
    const ushort* __restrict__ wqdcs, const float* __restrict__ decb,
    ushort* __restrict__ hbf) {
  __shared__ ushort A[EPB * NAS];
  __shared__ ushort m1[EPB * MS];
  __shared__ float nbuf[4 * EPB];
  const int tid = threadIdx.x;
  const int n0 = blockIdx.x * EPB;

  const int lane = tid & 63, wave = tid >> 6;
  const int lrow = lane & 15, lq = lane >> 4;
  const int wbase = wave * 32;

  short8b wef[8][2], wqf[4][2];
#pragma unroll
  for (int kt = 0; kt < 8; ++kt)
#pragma unroll
    for (int nt = 0; nt < 2; ++nt)
      wef[kt][nt] = *(const short8b*)(enccs + kt * 4096 + (wbase + nt * 16 + lrow) * 32 + lq * 8);
#pragma unroll
  for (int kt = 0; kt < 4; ++kt)
#pragma unroll
    for (int nt = 0; nt < 2; ++nt)
      wqf[kt][nt] = *(const short8b*)(wqdcs + kt * 4096 + (wbase + nt * 16 + lrow) * 32 + lq * 8);
  const float ebv[2] = {encb[wbase + lrow], encb[wbase + 16 + lrow]};
  const float dbv[2] = {decb[wbase + lrow], decb[wbase + 16 + lrow]};

  {
    const int e = tid >> 2, j = tid & 3;
    int node = n0 + e;
    if (node >= N_NODES) node = N_NODES - 1;
    if (j < 2) {
      const float4* s4 = (const float4*)(out_h + (size_t)node * HDIM + j * 64);
      ushort* dst = A + e * NAS + j * 64;
#pragma unroll
      for (int i = 0; i < 16; ++i) {
        float4 v = s4[i];
        ushort4 o;
        o.x = f2bf(v.x); o.y = f2bf(v.y); o.z = f2bf(v.z); o.w = f2bf(v.w);
        ((ushort4*)dst)[i] = o;
      }
    } else {
      const int s = cstart[node], en = cend[node];
      const bool hasAgg = en > s;
      const float4* a4 = (const float4*)(agg + (size_t)node * HDIM + (j - 2) * 64);
      const int bb0 = (s >> 6) + 1;
      const int bb1 = hasAgg ? ((en - 1) >> 6) : 0;
      ushort* dst = A + e * NAS + 128 + (j - 2) * 64;
#pragma unroll
      for (int i = 0; i < 16; ++i) {
        float4 v = hasAgg ? a4[i] : make_float4(0.f, 0.f, 0.f, 0.f);
        for (int bb = bb0; bb <= bb1; ++bb) {
          float4 hv = *(const float4*)(headp + (size_t)bb * HDIM + (j - 2) * 64 + i * 4);
          v.x += hv.x; v.y += hv.y; v.z += hv.z; v.w += hv.w;
        }
        ushort4 o;
        o.x = f2bf(v.x * 0.01f); o.y = f2bf(v.y * 0.01f);
        o.z = f2bf(v.z * 0.01f); o.w = f2bf(v.w * 0.01f);
        ((ushort4*)dst)[i] = o;
      }
    }
  }
  __syncthreads();

  f32x4 acc[4][2];
#pragma unroll
  for (int mt = 0; mt < 4; ++mt)
#pragma unroll
    for (int nt = 0; nt < 2; ++nt) acc[mt][nt] = (f32x4){0.f, 0.f, 0.f, 0.f};
#pragma unroll
  for (int kt = 0; kt < 8; ++kt) {
    short8b af[4];
#pragma unroll
    for (int mt = 0; mt < 4; ++mt)
      af[mt] = *(const short8b*)(A + (mt * 16 + lrow) * NAS + kt * 32 + lq * 8);
#pragma unroll
    for (int mt = 0; mt < 4; ++mt)
#pragma unroll
      for (int nt = 0; nt < 2; ++nt)
        acc[mt][nt] = __builtin_amdgcn_mfma_f32_16x16x32_bf16(af[mt], wef[kt][nt], acc[mt][nt], 0, 0, 0);
  }
#pragma unroll
  for (int mt = 0; mt < 4; ++mt) {
    float ssp[4] = {0.f, 0.f, 0.f, 0.f};
#pragma unroll
    for (int nt = 0; nt < 2; ++nt)
#pragma unroll
      for (int r = 0; r < 4; ++r) {
        acc[mt][nt][r] += ebv[nt];
        ssp[r] += acc[mt][nt][r] * acc[mt][nt][r];
      }
#pragma unroll
    for (int m = 1; m < 16; m <<= 1)
#pragma unroll
      for (int r = 0; r < 4; ++r) ssp[r] += __shfl_xor(ssp[r], m, 64);
    if (lrow == 0) {
#pragma unroll
      for (int r = 0; r < 4; ++r)
        nbuf[wave * EPB + mt * 16 + lq * 4 + r] = ssp[r];
    }
  }
  __syncthreads();
#pragma unroll
  for (int mt = 0; mt < 4; ++mt)
#pragma unroll
    for (int r = 0; r < 4; ++r) {
      const int row = mt * 16 + lq * 4 + r;
      float sum = nbuf[row] + nbuf[EPB + row] + nbuf[2 * EPB + row] + nbuf[3 * EPB + row];
      float inv = 1.0f / sqrtf(sum + 1e-12f);
#pragma unroll
      for (int nt = 0; nt < 2; ++nt)
        m1[row * MS + wbase + nt * 16 + lrow] = f2bf(acc[mt][nt][r] * inv);
    }
  __syncthreads();

  f32x4 acc2[4][2];
#pragma unroll
  for (int mt = 0; mt < 4; ++mt)
#pragma unroll
    for (int nt = 0; nt < 2; ++nt) acc2[mt][nt] = (f32x4){0.f, 0.f, 0.f, 0.f};
#pragma unroll
  for (int kt = 0; kt < 4; ++kt) {
    short8b af[4];
#pragma unroll
    for (int mt = 0; mt < 4; ++mt)
      af[mt] = *(const short8b*)(m1 + (mt * 16 + lrow) * MS + kt * 32 + lq * 8);
#pragma unroll
    for (int mt = 0; mt < 4; ++mt)
#pragma unroll
      for (int nt = 0; nt < 2; ++nt)
        acc2[mt][nt] = __builtin_amdgcn_mfma_f32_16x16x32_bf16(af[mt], wqf[kt][nt], acc2[mt][nt], 0, 0, 0);
  }
#pragma unroll
  for (int mt = 0; mt < 4; ++mt)
#pragma unroll
    for (int nt = 0; nt < 2; ++nt) {
      const int n = wbase + nt * 16 + lrow;
#pragma unroll
      for (int r = 0; r < 4; ++r) {
        const int node = n0 + mt * 16 + lq * 4 + r;
        if (node < N_NODES) {
          size_t off = (size_t)node * HDIM + n;
          float hn = out_h[off] + acc2[mt][nt][r] + dbv[nt];
          out_h[off] = hn;
          hbf[off] = f2bf(hn);
        }
      }
    }
}

// ==================== MFMA coordinate head: streamed weights ===============
__global__ __launch_bounds__(256, 4) void coord_mfma_kernel(
    const ushort* __restrict__ hbf, const int* __restrict__ ei,
    const float* __restrict__ x, const float* __restrict__ ea,
    const int* __restrict__ elist,
    const ushort* __restrict__ w1cs, const float* __restrict__ b1,
    const ushort* __restrict__ w2cs, const float* __restrict__ b2,
    const float* __restrict__ w3, float* __restrict__ xout) {
  __shared__ ushort A[EPB * AS];      // m1 overlays
  __shared__ int rows[EPB];
  __shared__ int colsA[EPB];
  __shared__ float pbuf[4 * EPB];
  __shared__ float tv[EPB];
  ushort* m1 = A;

  const int tid = threadIdx.x;
  const int lane = tid & 63, wave = tid >> 6;
  const int lrow = lane & 15, lq = lane >> 4;
  const int wbase = wave * 32;
  const int woff0 = (wbase + lrow) * 32 + lq * 8;
  const int woff1 = (wbase + 16 + lrow) * 32 + lq * 8;

  const float b1v[2] = {b1[wbase + lrow], b1[wbase + 16 + lrow]};
  const float b2v[2] = {b2[wbase + lrow], b2[wbase + 16 + lrow]};
  const float w3v[2] = {w3[wbase + lrow], w3[wbase + 16 + lrow]};

  const int i0 = blockIdx.x * EPB;
  {
    const int e = tid >> 2, j = tid & 3;
    const int edge = elist[i0 + e];
    const int r = ei[edge], c = ei[N_EDGES + edge];
    if (j == 0) { rows[e] = r; colsA[e] = c; }
    const uint4* hr = (const uint4*)(hbf + (size_t)r * HDIM + j * 32);
    const uint4* hc = (const uint4*)(hbf + (size_t)c * HDIM + j * 32);
    uint4* d1 = (uint4*)(A + e * AS + j * 32);
    uint4* d2 = (uint4*)(A + e * AS + 128 + j * 32);
    d1[0] = hr[0]; d1[1] = hr[1]; d1[2] = hr[2]; d1[3] = hr[3];
    d2[0] = hc[0]; d2[1] = hc[1]; d2[2] = hc[2]; d2[3] = hc[3];
    if (j == 3) {
      float dx = x[r * 3 + 0] - x[c * 3 + 0];
      float dy = x[r * 3 + 1] - x[c * 3 + 1];
      float dz = x[r * 3 + 2] - x[c * 3 + 2];
      ushort* dst = A + e * AS;
      dst[256] = f2bf(dx * dx + dy * dy + dz * dz);
      dst[257] = f2bf(ea[edge]);
#pragma unroll
      for (int z = 258; z < 288; ++z) dst[z] = 0;
    }
  }
  __syncthreads();   // s1: A ready

  f32x4 acc[4][2];
#pragma unroll
  for (int mt = 0; mt < 4; ++mt)
#pragma unroll
    for (int nt = 0; nt < 2; ++nt) acc[mt][nt] = (f32x4){0.f, 0.f, 0.f, 0.f};
  {
    short8b wcur0 = *(const short8b*)(w1cs + woff0);
    short8b wcur1 = *(const short8b*)(w1cs + woff1);
#pragma unroll
    for (int kt = 0; kt < 9; ++kt) {
      short8b wn0, wn1;
      if (kt < 8) {
        wn0 = *(const short8b*)(w1cs + (kt + 1) * 4096 + woff0);
        wn1 = *(const short8b*)(w1cs + (kt + 1) * 4096 + woff1);
      }
      short8b af[4];
#pragma unroll
      for (int mt = 0; mt < 4; ++mt)
        af[mt] = *(const short8b*)(A + (mt * 16 + lrow) * AS + kt * 32 + lq * 8);
#pragma unroll
      for (int mt = 0; mt < 4; ++mt) {
        acc[mt][0] = __builtin_amdgcn_mfma_f32_16x16x32_bf16(af[mt], wcur0, acc[mt][0], 0, 0, 0);
        acc[mt][1] = __builtin_amdgcn_mfma_f32_16x16x32_bf16(af[mt], wcur1, acc[mt][1], 0, 0, 0);
      }
      if (kt < 8) { wcur0 = wn0; wcur1 = wn1; }
    }
  }
  __syncthreads();   // s2: all A reads done (m1 overlays A)
#pragma unroll
  for (int mt = 0; mt < 4; ++mt)
#pragma unroll
    for (int nt = 0; nt < 2; ++nt)
#pragma unroll
      for (int r = 0; r < 4; ++r)
        m1[(mt * 16 + lq * 4 + r) * MS + wbase + nt * 16 + lrow] =
            f2bf(silu_f(acc[mt][nt][r] + b1v[nt]));
  __syncthreads();   // s3: m1 ready

  f32x4 acc2[4][2];
#pragma unroll
  for (int mt = 0; mt < 4; ++mt)
#pragma unroll
    for (int nt = 0; nt < 2; ++nt) acc2[mt][nt] = (f32x4){0.f, 0.f, 0.f, 0.f};
  {
    short8b wcur0 = *(const short8b*)(w2cs + woff0);
    short8b wcur1 = *(const short8b*)(w2cs + woff1);
#pragma unroll
    for (int kt = 0; kt < 4; ++kt) {
      short8b wn0, wn1;
      if (kt < 3) {
        wn0 = *(const short8b*)(w2cs + (kt + 1) * 4096 + woff0);
        wn1 = *(const short8b*)(w2cs + (kt + 1) * 4096 + woff1);
      }
      short8b af[4];
#pragma unroll
      for (int mt = 0; mt < 4; ++mt)
        af[mt] = *(const short8b*)(m1 + (mt * 16 + lrow) * MS + kt * 32 + lq * 8);
#pragma unroll
      for (int mt = 0; mt < 4; ++mt) {
        acc2[mt][0] = __builtin_amdgcn_mfma_f32_16x16x32_bf16(af[mt], wcur0, acc2[mt][0], 0, 0, 0);
        acc2[mt][1] = __builtin_amdgcn_mfma_f32_16x16x32_bf16(af[mt], wcur1, acc2[mt][1], 0, 0, 0);
      }
      if (kt < 3) { wcur0 = wn0; wcur1 = wn1; }
    }
  }
#pragma unroll
  for (int mt = 0; mt < 4; ++mt) {
    float p[4] = {0.f, 0.f, 0.f, 0.f};
#pragma unroll
    for (int nt = 0; nt < 2; ++nt)
#pragma unroll
      for (int r = 0; r < 4; ++r)
        p[r] += silu_f(acc2[mt][nt][r] + b2v[nt]) * w3v[nt];
#pragma unroll
    for (int m = 1; m < 16; m <<= 1)
#pragma unroll
      for (int r = 0; r < 4; ++r) p[r] += __shfl_xor(p[r], m, 64);
    if (lrow == 0) {
#pragma unroll
      for (int r = 0; r < 4; ++r)
        pbuf[wave * EPB + mt * 16 + lq * 4 + r] = p[r];
    }
  }
  __syncthreads();
  if (tid < EPB) {
    tv[tid] = (pbuf[tid] + pbuf[EPB + tid] + pbuf[2 * EPB + tid] + pbuf[3 * EPB + tid]) * 0.01f;
  }
  __syncthreads();
  if (tid < EPB) {
    const int e = tid;
    const int r_e = rows[e];
    const bool leader = (e == 0) || (rows[e - 1] != r_e);
    if (leader) {
      float sx = 0.f, sy = 0.f, sz = 0.f;
      int f = e;
      do {
        const int c = colsA[f];
        float dx = x[r_e * 3 + 0] - x[c * 3 + 0];
        float dy = x[r_e * 3 + 1] - x[c * 3 + 1];
        float dz = x[r_e * 3 + 2] - x[c * 3 + 2];
        float radial = dx * dx + dy * dy + dz * dz;
        float s = 1.0f / (sqrtf(radial + 1e-8f) + 1.0f);
        float t = tv[f];
        sx += dx * s * t; sy += dy * s * t; sz += dz * s * t;
        ++f;
      } while (f < EPB && rows[f] == r_e);
      atomicAdd(&xout[r_e * 3 + 0], sx);
      atomicAdd(&xout[r_e * 3 + 1], sy);
      atomicAdd(&xout[r_e * 3 + 2], sz);
    }
  }
}

extern "C" void kernel_launch(void* const* d_in, const int* in_sizes, int n_in,
                              void* d_out, int out_size, void* d_ws, size_t ws_size,
                              hipStream_t stream) {
  const float* h     = (const float*)d_in[0];
  const float* x     = (const float*)d_in[1];
  const int*   ei    = (const int*)d_in[2];
  const float* ea    = (const float*)d_in[3];
  const float* e_w1  = (const float*)d_in[4];
  const float* e_b1  = (const float*)d_in[5];
  const float* e_w2  = (const float*)d_in[6];
  const float* e_b2  = (const float*)d_in[7];
  const float* enc_w = (const float*)d_in[8];
  const float* enc_b = (const float*)d_in[9];
  const float* coeffs= (const float*)d_in[10];
  const float* A_re  = (const float*)d_in[11];
  const float* A_im  = (const float*)d_in[12];
  const float* dec_w = (const float*)d_in[13];
  const float* dec_b = (const float*)d_in[14];
  const float* c_w1  = (const float*)d_in[15];
  const float* c_b1  = (const float*)d_in[16];
  const float* c_w2  = (const float*)d_in[17];
  const float* c_b2  = (const float*)d_in[18];
  const float* c_w3  = (const float*)d_in[19];

  float* out = (float*)d_out;
  float* ws  = (float*)d_ws;

  // workspace layout (float offsets) — ~33.1 MB
  float*  agg    = ws;                          // 3,840,000
  float2* xa     = (float2*)(ws + 3840000);     // 131,072 f
  float2* xb     = (float2*)(ws + 3971072);     // 131,072 f
  float2* xt     = (float2*)(ws + 4102144);     // 131,072 f
  float2* qm     = (float2*)(ws + 4233216);     // 131,072 f
  float2* gkm    = (float2*)(ws + 4364288);     // 131,072 f
  float2* njm    = (float2*)(ws + 4495360);     // 131,072 f
  float2* um     = (float2*)(ws + 4626432);     //  65,536 f
  int*    cursor = (int*)(ws + 4724864);        //  30,000 (post-fill: CSR ends)
  int*    cstart = (int*)(ws + 4754864);        //  30,000 (CSR starts)
  int*    elist  = (int*)(ws + 4784864);        // 480,000
  float*  headp  = ws + 5264864;                // 7500*128 = 960,000
  ushort* hbf    = (ushort*)(ws + 6224864);     // 1,920,000 f
  ushort* w1cs   = (ushort*)(ws + 8144864);
  ushort* w2cs   = (ushort*)(ws + 8181728);
  ushort* cw1cs  = (ushort*)(ws + 8198112);
  ushort* cw2cs  = (ushort*)(ws + 8216544);
  ushort* enccs  = (ushort*)(ws + 8224736);
  ushort* wqdcs  = (ushort*)(ws + 8257504);

  // fused init: out = [h|x], hbf = bf16(h)   (1 launch, one pass)
  init_out_bf_kernel<<<3750, 256, 0, stream>>>(h, x, out, hbf);

  // counting sort of edges by destination row (cstart kept immutable)
  hipMemsetAsync(cursor, 0, N_NODES * sizeof(int), stream);
  count_kernel<<<1875, 256, 0, stream>>>(ei, cursor);
  scan_kernel<<<1, 1024, 0, stream>>>(cursor, cstart);
  fill_kernel<<<1875, 256, 0, stream>>>(ei, cursor, elist);

  // all static weight conversions in ONE launch (55 chunks)
  convert_all_kernel<<<880, 256, 0, stream>>>(e_w1, e_w2, enc_w, c_w1, c_w2,
                                              w1cs, w2cs, enccs, cw1cs, cw2cs);

  // quantum-operator precompute: Newton-Schulz inverse + tiny GEMM chain
  ns_init_kernel<<<dim3(64, 4), 256, 0, stream>>>(A_re, A_im, xa);
  float2* cur = xa;
  float2* nxt = xb;
  for (int it = 0; it < 3; ++it) {
    ns_bx_kernel<<<dim3(64, 4), 256, 0, stream>>>(A_re, A_im, cur, xt);
    ns_upd_kernel<<<dim3(64, 4), 256, 0, stream>>>(cur, xt, nxt);
    float2* tmp = cur; cur = nxt; nxt = tmp;
  }
  qmat_kernel<<<dim3(64, 4), 256, 0, stream>>>(A_re, A_im, cur, qm);
  gk_kernel<<<dim3(64, 4), 256, 0, stream>>>(coeffs, gkm);
  nj_kernel<<<dim3(64, 4), 256, 0, stream>>>(qm, gkm, njm);
  compose_kernel<<<dim3(64, 2), 256, 0, stream>>>(njm, um);
  wqd_kernel<<<dim3(64, 2), 256, 0, stream>>>(um, dec_w, wqdcs);  // direct bf16 chunks

  // two message-passing layers
  for (int l = 0; l < 2; ++l) {
    edge_mfma_kernel<<<N_EDGES / EPB, 256, 0, stream>>>(
        hbf, ei, x, ea, elist, cstart,
        w1cs + (size_t)l * 9 * 4096, e_b1 + l * HDIM,
        w2cs + (size_t)l * 4 * 4096, e_b2 + l * HDIM, agg, headp);
    node_mfma_kernel<<<(N_NODES + EPB - 1) / EPB, 256, 0, stream>>>(
        out, agg, cstart, cursor, headp,
        enccs + (size_t)l * 8 * 4096, enc_b + l * HDIM,
        wqdcs + (size_t)l * 4 * 4096, dec_b + l * HDIM, hbf);
  }

  // coordinate head
  coord_mfma_kernel<<<N_EDGES / EPB, 256, 0, stream>>>(
      hbf, ei, x, ea, elist, cw1cs, c_b1, cw2cs, c_b2, c_w3,
      out + (size_t)N_NODES * HDIM);
}